// Round 2
// baseline (330.877 us; speedup 1.0000x reference)
//
#include <hip/hip_runtime.h>

#define N_NODES 50000
#define N_EDGES 800000
#define NUM_GRAPHS 256
#define HID 128
#define IN_DIM 64
#define BN_EPS 1e-5f
#define SPREAD 16
#define NB 196            // buckets: dst>>8
#define BUCKET 256        // nodes per bucket
#define SCHUNK 4096       // edges per scatter block
#define NCHUNK 196        // ceil(N_EDGES/SCHUNK)
#define PX_BLKS 1563      // ceil(N_NODES*8/256)
#define W0_BLKS 8         // 8*4*64/256
#define W1_BLKS 16        // 8*8*64/256
#define GB_BLKS 196       // ceil(N_NODES/256) graph-boundary blocks

typedef __attribute__((ext_vector_type(8))) short bf16x8;
typedef __attribute__((ext_vector_type(4))) float f32x4;

// ---- bf16 helpers ----
__device__ __forceinline__ float bf2f(unsigned short u){ union{unsigned i;float f;}c; c.i=((unsigned)u)<<16; return c.f; }
__device__ __forceinline__ float bflo(unsigned w){ union{unsigned i;float f;}c; c.i=w<<16; return c.f; }
__device__ __forceinline__ float bfhi(unsigned w){ union{unsigned i;float f;}c; c.i=w&0xFFFF0000u; return c.f; }
__device__ __forceinline__ unsigned short f2bf(float f){ union{float f;unsigned i;}c; c.f=f; unsigned r=c.i+0x7FFF+((c.i>>16)&1); return (unsigned short)(r>>16); }
__device__ __forceinline__ unsigned fpack(float a, float b){
  union{float f;unsigned i;}ca,cb; ca.f=a; cb.f=b;
  unsigned ra=((ca.i+0x7FFF+((ca.i>>16)&1))>>16)&0xFFFFu;
  unsigned rb=(cb.i+0x7FFF+((cb.i>>16)&1))&0xFFFF0000u;
  return ra|rb;
}
__device__ __forceinline__ void acc8(float* a, uint4 u){
  a[0]+=bflo(u.x); a[1]+=bfhi(u.x); a[2]+=bflo(u.y); a[3]+=bfhi(u.y);
  a[4]+=bflo(u.z); a[5]+=bfhi(u.z); a[6]+=bflo(u.w); a[7]+=bfhi(u.w);
}

// ---------------- bucket histogram ----------------
__global__ __launch_bounds__(256) void k_hist(const int* __restrict__ dst, int* __restrict__ bcount){
  __shared__ int h[NB];
  int t = threadIdx.x;
  for(int i=t;i<NB;i+=256) h[i]=0;
  __syncthreads();
  int base = blockIdx.x*SCHUNK;
  int n = min(SCHUNK, N_EDGES-base);
  for(int v=t; v<n; v+=256) atomicAdd(&h[dst[base+v]>>8], 1);
  __syncthreads();
  for(int i=t;i<NB;i+=256) if(h[i]) atomicAdd(&bcount[i], h[i]);
}

// ---------------- fused: LDS-staged bucket scatter + packX + packW x3 + graph bounds ----------------
__global__ __launch_bounds__(256) void k_scatter_pack(const int* __restrict__ src, const int* __restrict__ dst,
      const int* __restrict__ bcount, int* __restrict__ bfill, unsigned* __restrict__ pairs,
      const float* __restrict__ x, unsigned short* __restrict__ H0,
      const float* __restrict__ Wn0, const float* __restrict__ Wr0, unsigned short* __restrict__ Bp0,
      const float* __restrict__ Wn1, const float* __restrict__ Wr1, unsigned short* __restrict__ Bp1,
      const float* __restrict__ Wn2, const float* __restrict__ Wr2, unsigned short* __restrict__ Bp2,
      const int* __restrict__ batch, int* __restrict__ gstart){
  __shared__ int h[NB], lbase[NB], gbase[NB], cur[NB];
  __shared__ int sc[256];
  __shared__ unsigned staged[SCHUNK];
  int blk = blockIdx.x, t = threadIdx.x;
  if(blk < NCHUNK){
    for(int i=t;i<NB;i+=256) h[i]=0;
    __syncthreads();
    int base = blk*SCHUNK;
    int n = min(SCHUNK, N_EDGES-base);
    for(int v=t; v<n; v+=256) atomicAdd(&h[dst[base+v]>>8], 1);
    __syncthreads();
    int bc = (t<NB)? bcount[t] : 0;
    sc[t]=bc; __syncthreads();
    for(int off=1;off<256;off<<=1){ int u=(t>=off)?sc[t-off]:0; __syncthreads(); sc[t]+=u; __syncthreads(); }
    int bb_t = sc[t]-bc;
    __syncthreads();
    int hv = (t<NB)? h[t] : 0;
    sc[t]=hv; __syncthreads();
    for(int off=1;off<256;off<<=1){ int u=(t>=off)?sc[t-off]:0; __syncthreads(); sc[t]+=u; __syncthreads(); }
    if(t<NB){ lbase[t]=sc[t]-hv; cur[t]=0; if(hv) gbase[t] = bb_t + atomicAdd(&bfill[t], hv); }
    __syncthreads();
    for(int v=t; v<n; v+=256){
      int s = src[base+v], d = dst[base+v];
      int b = d>>8;
      int rr = atomicAdd(&cur[b], 1);
      staged[lbase[b]+rr] = (unsigned)s | ((unsigned)(d&255)<<16) | ((unsigned)b<<24);
    }
    __syncthreads();
    for(int i=t; i<n; i+=256){
      unsigned p = staged[i];
      int b = (int)(p>>24);
      pairs[gbase[b] + (i - lbase[b])] = p;
    }
  } else if(blk < NCHUNK+PX_BLKS){
    int tid = (blk-NCHUNK)*256 + t;        // N_NODES*8 units of 8 feats
    if(tid < N_NODES*8){
      int row = tid>>3, q = tid&7;
      float4 a = ((const float4*)x)[(size_t)row*16 + q*2];
      float4 b = ((const float4*)x)[(size_t)row*16 + q*2 + 1];
      uint4 o;
      o.x = fpack(a.x,a.y); o.y = fpack(a.z,a.w);
      o.z = fpack(b.x,b.y); o.w = fpack(b.z,b.w);
      ((uint4*)H0)[(size_t)row*8 + q] = o;
    }
  } else if(blk < NCHUNK+PX_BLKS+W0_BLKS+2*W1_BLKS){
    const float *Wn, *Wr; unsigned short* Bp; int KH, base;
    if(blk < NCHUNK+PX_BLKS+W0_BLKS){ Wn=Wn0; Wr=Wr0; Bp=Bp0; KH=IN_DIM; base=NCHUNK+PX_BLKS; }
    else if(blk < NCHUNK+PX_BLKS+W0_BLKS+W1_BLKS){ Wn=Wn1; Wr=Wr1; Bp=Bp1; KH=HID; base=NCHUNK+PX_BLKS+W0_BLKS; }
    else { Wn=Wn2; Wr=Wr2; Bp=Bp2; KH=HID; base=NCHUNK+PX_BLKS+W0_BLKS+W1_BLKS; }
    int NKS = (2*KH)/32;
    int id = (blk-base)*256 + t;
    if(id < 8*NKS*64){
      int lane = id & 63;
      int ks = (id>>6) % NKS;
      int nt = (id>>6) / NKS;
      int quad = lane>>4, m = lane&15;
      int c = nt*16 + m;
      unsigned short v[8];
      #pragma unroll
      for(int j=0;j<8;j++){
        int k = ks*32 + quad*8 + j;
        float w = (k < KH) ? Wn[(size_t)k*HID + c] : Wr[(size_t)(k-KH)*HID + c];
        v[j] = f2bf(w);
      }
      uint4 o;
      o.x = ((unsigned)v[1]<<16)|v[0]; o.y = ((unsigned)v[3]<<16)|v[2];
      o.z = ((unsigned)v[5]<<16)|v[4]; o.w = ((unsigned)v[7]<<16)|v[6];
      ((uint4*)Bp)[id] = o;
    }
  } else {
    // graph boundary detection: gstart[g] = first node index with batch >= g (batch sorted)
    int id = (blk - (NCHUNK+PX_BLKS+W0_BLKS+2*W1_BLKS))*256 + t;
    if(id < N_NODES){
      int b = batch[id];
      if(id == 0){
        for(int g=0; g<=b; g++) gstart[g] = 0;
      } else {
        int pv = batch[id-1];
        if(pv != b) for(int g=pv+1; g<=b; g++) gstart[g] = id;
      }
      if(id == N_NODES-1){
        for(int g=b+1; g<=NUM_GRAPHS; g++) gstart[g] = N_NODES;
      }
    }
  }
}

// ---------------- per-bucket exact CSR (eidx as u16) ----------------
__global__ __launch_bounds__(1024) void k_csr(const unsigned* __restrict__ pairs, const int* __restrict__ bcount,
                int* __restrict__ rowptr, float* __restrict__ invdeg, unsigned short* __restrict__ eidx){
  __shared__ int cnt[BUCKET], cur[BUCKET], sc[BUCKET];
  __shared__ int bb[2];
  int t = threadIdx.x;
  int b = blockIdx.x;
  if(t==0){ bb[0]=0; bb[1]=0; }
  if(t<BUCKET) cnt[t]=0;
  __syncthreads();
  if(t<NB){
    int c = bcount[t];
    if(t<b)  atomicAdd(&bb[0], c);
    if(t<=b) atomicAdd(&bb[1], c);
  }
  __syncthreads();
  int e0 = bb[0], e1 = bb[1];
  int node0 = b*BUCKET;
  for(int i=e0+t; i<e1; i+=1024) atomicAdd(&cnt[(int)((pairs[i]>>16)&0xFF)], 1);
  __syncthreads();
  if(t<BUCKET) sc[t]=cnt[t];
  __syncthreads();
  for(int off=1;off<BUCKET;off<<=1){
    int u=0;
    if(t<BUCKET && t>=off) u=sc[t-off];
    __syncthreads();
    if(t<BUCKET) sc[t]+=u;
    __syncthreads();
  }
  if(t<BUCKET && node0+t < N_NODES){
    int pre = sc[t]-cnt[t] + e0;
    rowptr[node0+t] = pre;
    cur[t] = pre;
    invdeg[node0+t] = 1.0f/(float)max(cnt[t],1);
  }
  if(b==0 && t==0) rowptr[N_NODES] = N_EDGES;
  __syncthreads();
  for(int i=e0+t; i<e1; i+=1024){
    unsigned p = pairs[i];
    int pos = atomicAdd(&cur[(p>>16)&0xFF], 1);
    eidx[pos] = (unsigned short)(p & 0xFFFF);
  }
}

// ---------------- FUSED: mean-aggregate (wave-private, into LDS) + MFMA GEMM + col-stats ----------------
// Each block: 64 rows, 4 waves x 16 rows. Wave gathers its own 16 rows into its LDS quarter
// (no barrier needed: rows are wave-private), then runs the MFMA K-loop with A = [AGG_lds | H_global].
template<int KH>   // 64 or 128; K = 2*KH
__global__ __launch_bounds__(256) void k_agg_gemm(const unsigned short* __restrict__ H,
                     const unsigned short* __restrict__ eidx, const int* __restrict__ rowptr,
                     const float* __restrict__ invdeg,
                     const unsigned short* __restrict__ Bp, const float* __restrict__ bias,
                     unsigned short* __restrict__ raw,
                     float* __restrict__ psum, float* __restrict__ psq){
  const int NKS = (2*KH)/32;
  const int LKS = KH/32;
  const int F8  = KH/8;    // lanes per row-slice: 8 / 16
  const int RPI = 64/F8;   // rows (edges) in flight per wave-iter: 8 / 4
  const int LDA = KH + 4;  // +4 ushort pad: row stride 2 dwords mod 32 -> conflict-free frag reads
  __shared__ unsigned short Alds[64*LDA];
  int wave = threadIdx.x>>6, lane = threadIdx.x&63;
  int row0w = blockIdx.x*64 + wave*16;
  if(row0w >= N_NODES) return;

  // ---- gather phase: 16 nodes, wave-parallel over RPI edges x F8 feature-slices ----
  int r = lane / F8, q = lane % F8;
  unsigned short* Aw = Alds + wave*16*LDA;
  for(int nn=0; nn<16; nn++){
    int n = row0w + nn;
    int b = rowptr[n], e = rowptr[n+1];
    float acc[8] = {0,0,0,0,0,0,0,0};
    int i = b + r;
    for(; i + 3*RPI < e; i += 4*RPI){
      int s0 = eidx[i], s1 = eidx[i+RPI], s2 = eidx[i+2*RPI], s3 = eidx[i+3*RPI];
      uint4 u0 = *(const uint4*)(H + (size_t)s0*KH + q*8);
      uint4 u1 = *(const uint4*)(H + (size_t)s1*KH + q*8);
      uint4 u2 = *(const uint4*)(H + (size_t)s2*KH + q*8);
      uint4 u3 = *(const uint4*)(H + (size_t)s3*KH + q*8);
      acc8(acc,u0); acc8(acc,u1); acc8(acc,u2); acc8(acc,u3);
    }
    for(; i + RPI < e; i += 2*RPI){
      int s0 = eidx[i], s1 = eidx[i+RPI];
      uint4 u0 = *(const uint4*)(H + (size_t)s0*KH + q*8);
      uint4 u1 = *(const uint4*)(H + (size_t)s1*KH + q*8);
      acc8(acc,u0); acc8(acc,u1);
    }
    for(; i < e; i += RPI){
      int s0 = eidx[i];
      uint4 u0 = *(const uint4*)(H + (size_t)s0*KH + q*8);
      acc8(acc,u0);
    }
    #pragma unroll
    for(int off = F8; off < 64; off <<= 1){
      #pragma unroll
      for(int k=0;k<8;k++) acc[k] += __shfl_xor(acc[k], off, 64);
    }
    if(lane < F8){
      float id = invdeg[n];
      uint4 o;
      o.x = fpack(acc[0]*id, acc[1]*id); o.y = fpack(acc[2]*id, acc[3]*id);
      o.z = fpack(acc[4]*id, acc[5]*id); o.w = fpack(acc[6]*id, acc[7]*id);
      *(uint4*)(Aw + nn*LDA + lane*8) = o;
    }
  }

  // ---- GEMM phase (reads only this wave's 16 LDS rows; no __syncthreads needed) ----
  int m = lane&15, quad = lane>>4;
  const unsigned short* Arow = Aw + m*LDA + quad*8;
  const unsigned short* Hrow = H + (size_t)(row0w+m)*KH + quad*8;
  f32x4 facc[8];
  #pragma unroll
  for(int nt=0;nt<8;nt++) facc[nt] = (f32x4){0.f,0.f,0.f,0.f};
  #pragma unroll 1
  for(int ks=0; ks<NKS; ks++){
    bf16x8 a = (ks < LKS) ? *(const bf16x8*)(Arow + ks*32)
                          : *(const bf16x8*)(Hrow + (size_t)(ks-LKS)*32);
    const unsigned short* bp = Bp + ((size_t)ks*64 + lane)*8;
    #pragma unroll
    for(int nt=0;nt<8;nt++){
      bf16x8 b = *(const bf16x8*)(bp + (size_t)nt*NKS*64*8);
      facc[nt] = __builtin_amdgcn_mfma_f32_16x16x32_bf16(a, b, facc[nt], 0, 0, 0);
    }
  }
  int sp = blockIdx.x & (SPREAD-1);
  #pragma unroll
  for(int nt=0;nt<8;nt++){
    int col = nt*16 + m;
    float bv = bias[col];
    float s = 0.f, s2 = 0.f;
    #pragma unroll
    for(int reg=0;reg<4;reg++){
      float v = facc[nt][reg] + bv;
      int row = row0w + quad*4 + reg;
      raw[(size_t)row*HID + col] = f2bf(v);
      s += v; s2 += v*v;
    }
    s  += __shfl_xor(s, 16, 64);  s  += __shfl_xor(s, 32, 64);
    s2 += __shfl_xor(s2, 16, 64); s2 += __shfl_xor(s2, 32, 64);
    if(quad==0){
      atomicAdd(&psum[sp*HID+col], s);
      atomicAdd(&psq [sp*HID+col], s2);
    }
  }
}

// ---------------- BN+ReLU transform (inline stats reduce): raw -> H_next ----------------
__global__ __launch_bounds__(256) void k_transform(const unsigned short* __restrict__ raw,
      const float* __restrict__ psum, const float* __restrict__ psq,
      const float* __restrict__ gamma, const float* __restrict__ beta,
      unsigned short* __restrict__ Hout){
  __shared__ float s_sc[HID], s_sf[HID];
  int t = threadIdx.x;
  if(t < HID){
    float s=0.f, s2=0.f;
    #pragma unroll
    for(int i=0;i<SPREAD;i++){ s += psum[i*HID+t]; s2 += psq[i*HID+t]; }
    float mu  = s  * (1.0f/(float)N_NODES);
    float var = s2 * (1.0f/(float)N_NODES) - mu*mu;
    float rstd = rsqrtf(var + BN_EPS);
    float sc = rstd * gamma[t];
    s_sc[t] = sc; s_sf[t] = beta[t] - mu*sc;
  }
  __syncthreads();
  int tid = blockIdx.x*256 + t;   // N_NODES*16 uint4 units
  if(tid >= N_NODES*16) return;
  int q = tid & 15;
  uint4 u = ((const uint4*)raw)[tid];
  float f0 = fmaxf(fmaf(bflo(u.x), s_sc[q*8+0], s_sf[q*8+0]), 0.f);
  float f1 = fmaxf(fmaf(bfhi(u.x), s_sc[q*8+1], s_sf[q*8+1]), 0.f);
  float f2 = fmaxf(fmaf(bflo(u.y), s_sc[q*8+2], s_sf[q*8+2]), 0.f);
  float f3 = fmaxf(fmaf(bfhi(u.y), s_sc[q*8+3], s_sf[q*8+3]), 0.f);
  float f4 = fmaxf(fmaf(bflo(u.z), s_sc[q*8+4], s_sf[q*8+4]), 0.f);
  float f5 = fmaxf(fmaf(bfhi(u.z), s_sc[q*8+5], s_sf[q*8+5]), 0.f);
  float f6 = fmaxf(fmaf(bflo(u.w), s_sc[q*8+6], s_sf[q*8+6]), 0.f);
  float f7 = fmaxf(fmaf(bfhi(u.w), s_sc[q*8+7], s_sf[q*8+7]), 0.f);
  uint4 o;
  o.x = fpack(f0,f1); o.y = fpack(f2,f3); o.z = fpack(f4,f5); o.w = fpack(f6,f7);
  ((uint4*)Hout)[tid] = o;
}

// ---------------- FUSED: global mean pool (one block per graph, no atomics) + BN2 + ReLU + MLP head ----------------
__global__ __launch_bounds__(256) void k_poolmlp(const unsigned short* __restrict__ raw,
      const int* __restrict__ gstart,
      const float* __restrict__ psum, const float* __restrict__ psq,
      const float* __restrict__ gamma, const float* __restrict__ beta,
      const float* __restrict__ fc1W, const float* __restrict__ fc1b,
      const float* __restrict__ fc2W, const float* __restrict__ fc2b,
      float* __restrict__ out){
  __shared__ float s_sc[HID], s_sf[HID];
  __shared__ float red[16][HID];
  __shared__ float p[HID];
  int g = blockIdx.x, t = threadIdx.x;
  if(t < HID){
    float s=0.f, s2=0.f;
    #pragma unroll
    for(int i=0;i<SPREAD;i++){ s += psum[i*HID+t]; s2 += psq[i*HID+t]; }
    float mu  = s  * (1.0f/(float)N_NODES);
    float var = s2 * (1.0f/(float)N_NODES) - mu*mu;
    float rstd = rsqrtf(var + BN_EPS);
    float sc = rstd * gamma[t];
    s_sc[t] = sc; s_sf[t] = beta[t] - mu*sc;
  }
  __syncthreads();
  int r0 = gstart[g], r1 = gstart[g+1];
  int q = t & 15, rr = t >> 4;   // 16 row-groups x 16 feature-slices
  float acc[8] = {0,0,0,0,0,0,0,0};
  for(int n = r0 + rr; n < r1; n += 16){
    uint4 u = ((const uint4*)raw)[(size_t)n*16 + q];
    acc[0] += fmaxf(fmaf(bflo(u.x), s_sc[q*8+0], s_sf[q*8+0]), 0.f);
    acc[1] += fmaxf(fmaf(bfhi(u.x), s_sc[q*8+1], s_sf[q*8+1]), 0.f);
    acc[2] += fmaxf(fmaf(bflo(u.y), s_sc[q*8+2], s_sf[q*8+2]), 0.f);
    acc[3] += fmaxf(fmaf(bfhi(u.y), s_sc[q*8+3], s_sf[q*8+3]), 0.f);
    acc[4] += fmaxf(fmaf(bflo(u.z), s_sc[q*8+4], s_sf[q*8+4]), 0.f);
    acc[5] += fmaxf(fmaf(bfhi(u.z), s_sc[q*8+5], s_sf[q*8+5]), 0.f);
    acc[6] += fmaxf(fmaf(bflo(u.w), s_sc[q*8+6], s_sf[q*8+6]), 0.f);
    acc[7] += fmaxf(fmaf(bfhi(u.w), s_sc[q*8+7], s_sf[q*8+7]), 0.f);
  }
  #pragma unroll
  for(int k=0;k<8;k++) red[rr][q*8+k] = acc[k];
  __syncthreads();
  if(t < HID){
    float s = 0.f;
    #pragma unroll
    for(int j=0;j<16;j++) s += red[j][t];
    float ic = 1.0f / fmaxf((float)(r1 - r0), 1.0f);
    p[t] = s * ic;
  }
  __syncthreads();
  if(t < 64){
    float z = fc1b[t];
    #pragma unroll 4
    for(int k=0;k<HID;k++) z += p[k]*fc1W[k*64 + t];
    z = fmaxf(z, 0.f);
    float v = z * fc2W[t];
    #pragma unroll
    for(int off=32; off>0; off>>=1) v += __shfl_down(v, off, 64);
    if(t==0) out[g] = 1.0f/(1.0f + expf(-(v + fc2b[0])));
  }
}

extern "C" void kernel_launch(void* const* d_in, const int* in_sizes, int n_in,
                              void* d_out, int out_size, void* d_ws, size_t ws_size,
                              hipStream_t stream){
  const float* x    = (const float*)d_in[0];
  const int*   ei   = (const int*)d_in[1];
  const int*   batch= (const int*)d_in[2];
  const float* Wn0=(const float*)d_in[3]; const float* Wr0=(const float*)d_in[4]; const float* b0=(const float*)d_in[5];
  const float* Wn1=(const float*)d_in[6]; const float* Wr1=(const float*)d_in[7]; const float* b1=(const float*)d_in[8];
  const float* Wn2=(const float*)d_in[9]; const float* Wr2=(const float*)d_in[10]; const float* b2=(const float*)d_in[11];
  const float* gamma=(const float*)d_in[12]; const float* beta=(const float*)d_in[13];
  const float* fc1W=(const float*)d_in[14]; const float* fc1b=(const float*)d_in[15];
  const float* fc2W=(const float*)d_in[16]; const float* fc2b=(const float*)d_in[17];
  float* out = (float*)d_out;

  char* ws = (char*)d_ws;
  size_t off = 0;
  auto alloc = [&](size_t bytes)->char*{ char* p = ws + off; off += (bytes + 255) & ~(size_t)255; return p; };

  // --- zeroed region (single memset): bcount | bfill | pstats ---
  char* zero0   = ws + off;
  int*   bcount = (int*)alloc((size_t)NB*4);
  int*   bfill  = (int*)alloc((size_t)NB*4);
  float* pstats = (float*)alloc((size_t)3*2*SPREAD*HID*4);
  size_t zbytes = (size_t)((ws + off) - zero0);

  // --- non-zeroed scratch ---
  unsigned short* H0  = (unsigned short*)alloc((size_t)N_NODES*IN_DIM*2);
  unsigned short* H1  = (unsigned short*)alloc((size_t)N_NODES*HID*2);
  unsigned short* H2  = (unsigned short*)alloc((size_t)N_NODES*HID*2);
  unsigned short* raw = (unsigned short*)alloc((size_t)N_NODES*HID*2);
  unsigned short* Bp0 = (unsigned short*)alloc((size_t)8*4*64*8*2);
  unsigned short* Bp1 = (unsigned short*)alloc((size_t)8*8*64*8*2);
  unsigned short* Bp2 = (unsigned short*)alloc((size_t)8*8*64*8*2);
  float* invdeg = (float*)alloc((size_t)N_NODES*4);
  int* rowptr   = (int*)alloc((size_t)(N_NODES+1)*4);
  unsigned short* eidx = (unsigned short*)alloc((size_t)N_EDGES*2);
  unsigned* pairs = (unsigned*)alloc((size_t)N_EDGES*4);
  int* gstart   = (int*)alloc((size_t)(NUM_GRAPHS+1)*4);

  auto psumL = [&](int l){ return pstats + (size_t)l*2*SPREAD*HID; };
  auto psqL  = [&](int l){ return pstats + (size_t)l*2*SPREAD*HID + (size_t)SPREAD*HID; };

  const int* src = ei;
  const int* dst = ei + N_EDGES;

  hipMemsetAsync(zero0, 0, zbytes, stream);

  // CSR build + packs + graph bounds (ride along with scatter dispatch)
  k_hist<<<NCHUNK, 256, 0, stream>>>(dst, bcount);
  k_scatter_pack<<<NCHUNK+PX_BLKS+W0_BLKS+2*W1_BLKS+GB_BLKS, 256, 0, stream>>>(src, dst, bcount, bfill, pairs,
      x, H0, Wn0, Wr0, Bp0, Wn1, Wr1, Bp1, Wn2, Wr2, Bp2, batch, gstart);
  k_csr<<<NB, 1024, 0, stream>>>(pairs, bcount, rowptr, invdeg, eidx);

  const int GEMM_BLKS = (N_NODES + 63)/64;   // 782

  // ---- layer 0 ----
  k_agg_gemm<IN_DIM><<<GEMM_BLKS, 256, 0, stream>>>(H0, eidx, rowptr, invdeg, Bp0, b0, raw, psumL(0), psqL(0));
  k_transform<<<(N_NODES*16)/256, 256, 0, stream>>>(raw, psumL(0), psqL(0), gamma+0*HID, beta+0*HID, H1);
  // ---- layer 1 ----
  k_agg_gemm<HID><<<GEMM_BLKS, 256, 0, stream>>>(H1, eidx, rowptr, invdeg, Bp1, b1, raw, psumL(1), psqL(1));
  k_transform<<<(N_NODES*16)/256, 256, 0, stream>>>(raw, psumL(1), psqL(1), gamma+1*HID, beta+1*HID, H2);
  // ---- layer 2 ----
  k_agg_gemm<HID><<<GEMM_BLKS, 256, 0, stream>>>(H2, eidx, rowptr, invdeg, Bp2, b2, raw, psumL(2), psqL(2));

  // ---- fused pool + BN2 + ReLU + MLP head (one block per graph, no atomics) ----
  k_poolmlp<<<NUM_GRAPHS, 256, 0, stream>>>(raw, gstart, psumL(2), psqL(2), gamma+2*HID, beta+2*HID,
      fc1W, fc1b, fc2W, fc2b, out);
}

// Round 5
// 280.822 us; speedup vs baseline: 1.1782x; 1.1782x over previous
//
#include <hip/hip_runtime.h>

#define N_NODES 50000
#define N_EDGES 800000
#define NUM_GRAPHS 256
#define HID 128
#define IN_DIM 64
#define BN_EPS 1e-5f
#define SPREAD 16
#define NB 196            // buckets: dst>>8
#define BUCKET 256        // nodes per bucket
#define SCHUNK 4096       // edges per scatter block
#define NCHUNK 196        // ceil(N_EDGES/SCHUNK)
#define PX_BLKS 1563      // ceil(N_NODES*8/256)
#define W0_BLKS 8         // 8*4*64/256
#define W1_BLKS 16        // 8*8*64/256
#define GB_BLKS 196       // ceil(N_NODES/256) graph-boundary blocks

typedef __attribute__((ext_vector_type(8))) short bf16x8;
typedef __attribute__((ext_vector_type(4))) float f32x4;

// ---- bf16 helpers ----
__device__ __forceinline__ float bf2f(unsigned short u){ union{unsigned i;float f;}c; c.i=((unsigned)u)<<16; return c.f; }
__device__ __forceinline__ float bflo(unsigned w){ union{unsigned i;float f;}c; c.i=w<<16; return c.f; }
__device__ __forceinline__ float bfhi(unsigned w){ union{unsigned i;float f;}c; c.i=w&0xFFFF0000u; return c.f; }
__device__ __forceinline__ unsigned short f2bf(float f){ union{float f;unsigned i;}c; c.f=f; unsigned r=c.i+0x7FFF+((c.i>>16)&1); return (unsigned short)(r>>16); }
__device__ __forceinline__ unsigned fpack(float a, float b){
  union{float f;unsigned i;}ca,cb; ca.f=a; cb.f=b;
  unsigned ra=((ca.i+0x7FFF+((ca.i>>16)&1))>>16)&0xFFFFu;
  unsigned rb=(cb.i+0x7FFF+((cb.i>>16)&1))&0xFFFF0000u;
  return ra|rb;
}
__device__ __forceinline__ void acc8(float* a, uint4 u){
  a[0]+=bflo(u.x); a[1]+=bfhi(u.x); a[2]+=bflo(u.y); a[3]+=bfhi(u.y);
  a[4]+=bflo(u.z); a[5]+=bfhi(u.z); a[6]+=bflo(u.w); a[7]+=bfhi(u.w);
}

// ---------------- bucket histogram ----------------
__global__ __launch_bounds__(256) void k_hist(const int* __restrict__ dst, int* __restrict__ bcount){
  __shared__ int h[NB];
  int t = threadIdx.x;
  for(int i=t;i<NB;i+=256) h[i]=0;
  __syncthreads();
  int base = blockIdx.x*SCHUNK;
  int n = min(SCHUNK, N_EDGES-base);
  for(int v=t; v<n; v+=256) atomicAdd(&h[dst[base+v]>>8], 1);
  __syncthreads();
  for(int i=t;i<NB;i+=256) if(h[i]) atomicAdd(&bcount[i], h[i]);
}

// ---------------- fused: LDS-staged bucket scatter + packX + packW x3 + graph bounds ----------------
__global__ __launch_bounds__(256) void k_scatter_pack(const int* __restrict__ src, const int* __restrict__ dst,
      const int* __restrict__ bcount, int* __restrict__ bfill, unsigned* __restrict__ pairs,
      const float* __restrict__ x, unsigned short* __restrict__ H0,
      const float* __restrict__ Wn0, const float* __restrict__ Wr0, unsigned short* __restrict__ Bp0,
      const float* __restrict__ Wn1, const float* __restrict__ Wr1, unsigned short* __restrict__ Bp1,
      const float* __restrict__ Wn2, const float* __restrict__ Wr2, unsigned short* __restrict__ Bp2,
      const int* __restrict__ batch, int* __restrict__ gstart){
  __shared__ int h[NB], lbase[NB], gbase[NB], cur[NB];
  __shared__ int sc[256];
  __shared__ unsigned staged[SCHUNK];
  int blk = blockIdx.x, t = threadIdx.x;
  if(blk < NCHUNK){
    for(int i=t;i<NB;i+=256) h[i]=0;
    __syncthreads();
    int base = blk*SCHUNK;
    int n = min(SCHUNK, N_EDGES-base);
    for(int v=t; v<n; v+=256) atomicAdd(&h[dst[base+v]>>8], 1);
    __syncthreads();
    int bc = (t<NB)? bcount[t] : 0;
    sc[t]=bc; __syncthreads();
    for(int off=1;off<256;off<<=1){ int u=(t>=off)?sc[t-off]:0; __syncthreads(); sc[t]+=u; __syncthreads(); }
    int bb_t = sc[t]-bc;
    __syncthreads();
    int hv = (t<NB)? h[t] : 0;
    sc[t]=hv; __syncthreads();
    for(int off=1;off<256;off<<=1){ int u=(t>=off)?sc[t-off]:0; __syncthreads(); sc[t]+=u; __syncthreads(); }
    if(t<NB){ lbase[t]=sc[t]-hv; cur[t]=0; if(hv) gbase[t] = bb_t + atomicAdd(&bfill[t], hv); }
    __syncthreads();
    for(int v=t; v<n; v+=256){
      int s = src[base+v], d = dst[base+v];
      int b = d>>8;
      int rr = atomicAdd(&cur[b], 1);
      staged[lbase[b]+rr] = (unsigned)s | ((unsigned)(d&255)<<16) | ((unsigned)b<<24);
    }
    __syncthreads();
    for(int i=t; i<n; i+=256){
      unsigned p = staged[i];
      int b = (int)(p>>24);
      pairs[gbase[b] + (i - lbase[b])] = p;
    }
  } else if(blk < NCHUNK+PX_BLKS){
    int tid = (blk-NCHUNK)*256 + t;        // N_NODES*8 units of 8 feats
    if(tid < N_NODES*8){
      int row = tid>>3, q = tid&7;
      float4 a = ((const float4*)x)[(size_t)row*16 + q*2];
      float4 b = ((const float4*)x)[(size_t)row*16 + q*2 + 1];
      uint4 o;
      o.x = fpack(a.x,a.y); o.y = fpack(a.z,a.w);
      o.z = fpack(b.x,b.y); o.w = fpack(b.z,b.w);
      ((uint4*)H0)[(size_t)row*8 + q] = o;
    }
  } else if(blk < NCHUNK+PX_BLKS+W0_BLKS+2*W1_BLKS){
    const float *Wn, *Wr; unsigned short* Bp; int KH, base;
    if(blk < NCHUNK+PX_BLKS+W0_BLKS){ Wn=Wn0; Wr=Wr0; Bp=Bp0; KH=IN_DIM; base=NCHUNK+PX_BLKS; }
    else if(blk < NCHUNK+PX_BLKS+W0_BLKS+W1_BLKS){ Wn=Wn1; Wr=Wr1; Bp=Bp1; KH=HID; base=NCHUNK+PX_BLKS+W0_BLKS; }
    else { Wn=Wn2; Wr=Wr2; Bp=Bp2; KH=HID; base=NCHUNK+PX_BLKS+W0_BLKS+W1_BLKS; }
    int NKS = (2*KH)/32;
    int id = (blk-base)*256 + t;
    if(id < 8*NKS*64){
      int lane = id & 63;
      int ks = (id>>6) % NKS;
      int nt = (id>>6) / NKS;
      int quad = lane>>4, m = lane&15;
      int c = nt*16 + m;
      unsigned short v[8];
      #pragma unroll
      for(int j=0;j<8;j++){
        int k = ks*32 + quad*8 + j;
        float w = (k < KH) ? Wn[(size_t)k*HID + c] : Wr[(size_t)(k-KH)*HID + c];
        v[j] = f2bf(w);
      }
      uint4 o;
      o.x = ((unsigned)v[1]<<16)|v[0]; o.y = ((unsigned)v[3]<<16)|v[2];
      o.z = ((unsigned)v[5]<<16)|v[4]; o.w = ((unsigned)v[7]<<16)|v[6];
      ((uint4*)Bp)[id] = o;
    }
  } else {
    // graph boundary detection: gstart[g] = first node index with batch >= g (batch sorted)
    int id = (blk - (NCHUNK+PX_BLKS+W0_BLKS+2*W1_BLKS))*256 + t;
    if(id < N_NODES){
      int b = batch[id];
      if(id == 0){
        for(int g=0; g<=b; g++) gstart[g] = 0;
      } else {
        int pv = batch[id-1];
        if(pv != b) for(int g=pv+1; g<=b; g++) gstart[g] = id;
      }
      if(id == N_NODES-1){
        for(int g=b+1; g<=NUM_GRAPHS; g++) gstart[g] = N_NODES;
      }
    }
  }
}

// ---------------- per-bucket exact CSR (eidx as u16) ----------------
__global__ __launch_bounds__(1024) void k_csr(const unsigned* __restrict__ pairs, const int* __restrict__ bcount,
                int* __restrict__ rowptr, float* __restrict__ invdeg, unsigned short* __restrict__ eidx){
  __shared__ int cnt[BUCKET], cur[BUCKET], sc[BUCKET];
  __shared__ int bb[2];
  int t = threadIdx.x;
  int b = blockIdx.x;
  if(t==0){ bb[0]=0; bb[1]=0; }
  if(t<BUCKET) cnt[t]=0;
  __syncthreads();
  if(t<NB){
    int c = bcount[t];
    if(t<b)  atomicAdd(&bb[0], c);
    if(t<=b) atomicAdd(&bb[1], c);
  }
  __syncthreads();
  int e0 = bb[0], e1 = bb[1];
  int node0 = b*BUCKET;
  for(int i=e0+t; i<e1; i+=1024) atomicAdd(&cnt[(int)((pairs[i]>>16)&0xFF)], 1);
  __syncthreads();
  if(t<BUCKET) sc[t]=cnt[t];
  __syncthreads();
  for(int off=1;off<BUCKET;off<<=1){
    int u=0;
    if(t<BUCKET && t>=off) u=sc[t-off];
    __syncthreads();
    if(t<BUCKET) sc[t]+=u;
    __syncthreads();
  }
  if(t<BUCKET && node0+t < N_NODES){
    int pre = sc[t]-cnt[t] + e0;
    rowptr[node0+t] = pre;
    cur[t] = pre;
    invdeg[node0+t] = 1.0f/(float)max(cnt[t],1);
  }
  if(b==0 && t==0) rowptr[N_NODES] = N_EDGES;
  __syncthreads();
  for(int i=e0+t; i<e1; i+=1024){
    unsigned p = pairs[i];
    int pos = atomicAdd(&cur[(p>>16)&0xFF], 1);
    eidx[pos] = (unsigned short)(p & 0xFFFF);
  }
}

// ---------------- FUSED: mean-aggregate + MFMA GEMM + col-stats, TLP-restored ----------------
// 32 rows per block, 4 waves. Gather: each wave aggregates 8 rows into shared LDS
// (2x waves vs before, 8 serial nodes/wave vs 16). One barrier. GEMM: each wave owns
// a 16-row x 64-col tile (rt = w>>1, col-half = w&1).
template<int KH>   // 64 or 128; K = 2*KH
__global__ __launch_bounds__(256) void k_agg_gemm(const unsigned short* __restrict__ H,
                     const unsigned short* __restrict__ eidx, const int* __restrict__ rowptr,
                     const float* __restrict__ invdeg,
                     const unsigned short* __restrict__ Bp, const float* __restrict__ bias,
                     unsigned short* __restrict__ raw,
                     float* __restrict__ psum, float* __restrict__ psq){
  const int NKS = (2*KH)/32;
  const int LKS = KH/32;
  const int F8  = KH/8;    // lanes per row-slice: 8 / 16
  const int RPI = 64/F8;   // rows (edges) in flight per wave-iter: 8 / 4
  const int LDA = KH + 4;  // +4 ushort pad: conflict-free frag reads
  __shared__ unsigned short Alds[32*LDA];
  int wave = threadIdx.x>>6, lane = threadIdx.x&63;
  int row0b = blockIdx.x*32;

  // ---- gather phase: wave aggregates 8 rows into LDS ----
  int r = lane / F8, q = lane % F8;
  for(int j=0; j<8; j++){
    int li = wave*8 + j;           // row within block
    int n = row0b + li;
    if(n >= N_NODES) break;
    int b = rowptr[n], e = rowptr[n+1];
    float acc[8] = {0,0,0,0,0,0,0,0};
    int i = b + r;
    for(; i + 3*RPI < e; i += 4*RPI){
      int s0 = eidx[i], s1 = eidx[i+RPI], s2 = eidx[i+2*RPI], s3 = eidx[i+3*RPI];
      uint4 u0 = *(const uint4*)(H + (size_t)s0*KH + q*8);
      uint4 u1 = *(const uint4*)(H + (size_t)s1*KH + q*8);
      uint4 u2 = *(const uint4*)(H + (size_t)s2*KH + q*8);
      uint4 u3 = *(const uint4*)(H + (size_t)s3*KH + q*8);
      acc8(acc,u0); acc8(acc,u1); acc8(acc,u2); acc8(acc,u3);
    }
    for(; i + RPI < e; i += 2*RPI){
      int s0 = eidx[i], s1 = eidx[i+RPI];
      uint4 u0 = *(const uint4*)(H + (size_t)s0*KH + q*8);
      uint4 u1 = *(const uint4*)(H + (size_t)s1*KH + q*8);
      acc8(acc,u0); acc8(acc,u1);
    }
    for(; i < e; i += RPI){
      int s0 = eidx[i];
      uint4 u0 = *(const uint4*)(H + (size_t)s0*KH + q*8);
      acc8(acc,u0);
    }
    #pragma unroll
    for(int off = F8; off < 64; off <<= 1){
      #pragma unroll
      for(int k=0;k<8;k++) acc[k] += __shfl_xor(acc[k], off, 64);
    }
    if(lane < F8){
      float id = invdeg[n];
      uint4 o;
      o.x = fpack(acc[0]*id, acc[1]*id); o.y = fpack(acc[2]*id, acc[3]*id);
      o.z = fpack(acc[4]*id, acc[5]*id); o.w = fpack(acc[6]*id, acc[7]*id);
      *(uint4*)(Alds + li*LDA + lane*8) = o;
    }
  }
  __syncthreads();

  // ---- GEMM phase: wave tile = 16 rows x 64 cols ----
  int rt = wave>>1, ch = wave&1;
  int row0w = row0b + rt*16;
  if(row0w >= N_NODES) return;
  int m = lane&15, quad = lane>>4;
  const unsigned short* Arow = Alds + (rt*16 + m)*LDA + quad*8;
  const unsigned short* Hrow = H + (size_t)(row0w+m)*KH + quad*8;
  f32x4 facc[4];
  #pragma unroll
  for(int nt=0;nt<4;nt++) facc[nt] = (f32x4){0.f,0.f,0.f,0.f};
  #pragma unroll 1
  for(int ks=0; ks<NKS; ks++){
    bf16x8 a = (ks < LKS) ? *(const bf16x8*)(Arow + ks*32)
                          : *(const bf16x8*)(Hrow + (size_t)(ks-LKS)*32);
    const unsigned short* bp = Bp + ((size_t)ks*64 + lane)*8 + (size_t)ch*4*NKS*64*8;
    #pragma unroll
    for(int nt=0;nt<4;nt++){
      bf16x8 b = *(const bf16x8*)(bp + (size_t)nt*NKS*64*8);
      facc[nt] = __builtin_amdgcn_mfma_f32_16x16x32_bf16(a, b, facc[nt], 0, 0, 0);
    }
  }
  int sp = blockIdx.x & (SPREAD-1);
  #pragma unroll
  for(int nt=0;nt<4;nt++){
    int col = (ch*4 + nt)*16 + m;
    float bv = bias[col];
    float s = 0.f, s2 = 0.f;
    #pragma unroll
    for(int reg=0;reg<4;reg++){
      float v = facc[nt][reg] + bv;
      int row = row0w + quad*4 + reg;
      raw[(size_t)row*HID + col] = f2bf(v);
      s += v; s2 += v*v;
    }
    s  += __shfl_xor(s, 16, 64);  s  += __shfl_xor(s, 32, 64);
    s2 += __shfl_xor(s2, 16, 64); s2 += __shfl_xor(s2, 32, 64);
    if(quad==0){
      atomicAdd(&psum[sp*HID+col], s);
      atomicAdd(&psq [sp*HID+col], s2);
    }
  }
}

// ---------------- BN+ReLU transform (inline stats reduce): raw -> H_next ----------------
__global__ __launch_bounds__(256) void k_transform(const unsigned short* __restrict__ raw,
      const float* __restrict__ psum, const float* __restrict__ psq,
      const float* __restrict__ gamma, const float* __restrict__ beta,
      unsigned short* __restrict__ Hout){
  __shared__ float s_sc[HID], s_sf[HID];
  int t = threadIdx.x;
  if(t < HID){
    float s=0.f, s2=0.f;
    #pragma unroll
    for(int i=0;i<SPREAD;i++){ s += psum[i*HID+t]; s2 += psq[i*HID+t]; }
    float mu  = s  * (1.0f/(float)N_NODES);
    float var = s2 * (1.0f/(float)N_NODES) - mu*mu;
    float rstd = rsqrtf(var + BN_EPS);
    float sc = rstd * gamma[t];
    s_sc[t] = sc; s_sf[t] = beta[t] - mu*sc;
  }
  __syncthreads();
  int tid = blockIdx.x*256 + t;   // N_NODES*16 uint4 units
  if(tid >= N_NODES*16) return;
  int q = tid & 15;
  uint4 u = ((const uint4*)raw)[tid];
  float f0 = fmaxf(fmaf(bflo(u.x), s_sc[q*8+0], s_sf[q*8+0]), 0.f);
  float f1 = fmaxf(fmaf(bfhi(u.x), s_sc[q*8+1], s_sf[q*8+1]), 0.f);
  float f2 = fmaxf(fmaf(bflo(u.y), s_sc[q*8+2], s_sf[q*8+2]), 0.f);
  float f3 = fmaxf(fmaf(bfhi(u.y), s_sc[q*8+3], s_sf[q*8+3]), 0.f);
  float f4 = fmaxf(fmaf(bflo(u.z), s_sc[q*8+4], s_sf[q*8+4]), 0.f);
  float f5 = fmaxf(fmaf(bfhi(u.z), s_sc[q*8+5], s_sf[q*8+5]), 0.f);
  float f6 = fmaxf(fmaf(bflo(u.w), s_sc[q*8+6], s_sf[q*8+6]), 0.f);
  float f7 = fmaxf(fmaf(bfhi(u.w), s_sc[q*8+7], s_sf[q*8+7]), 0.f);
  uint4 o;
  o.x = fpack(f0,f1); o.y = fpack(f2,f3); o.z = fpack(f4,f5); o.w = fpack(f6,f7);
  ((uint4*)Hout)[tid] = o;
}

// ---------------- FUSED: global mean pool (one block per graph, no atomics) + BN2 + ReLU + MLP head ----------------
__global__ __launch_bounds__(256) void k_poolmlp(const unsigned short* __restrict__ raw,
      const int* __restrict__ gstart,
      const float* __restrict__ psum, const float* __restrict__ psq,
      const float* __restrict__ gamma, const float* __restrict__ beta,
      const float* __restrict__ fc1W, const float* __restrict__ fc1b,
      const float* __restrict__ fc2W, const float* __restrict__ fc2b,
      float* __restrict__ out){
  __shared__ float s_sc[HID], s_sf[HID];
  __shared__ float red[16][HID];
  __shared__ float p[HID];
  int g = blockIdx.x, t = threadIdx.x;
  if(t < HID){
    float s=0.f, s2=0.f;
    #pragma unroll
    for(int i=0;i<SPREAD;i++){ s += psum[i*HID+t]; s2 += psq[i*HID+t]; }
    float mu  = s  * (1.0f/(float)N_NODES);
    float var = s2 * (1.0f/(float)N_NODES) - mu*mu;
    float rstd = rsqrtf(var + BN_EPS);
    float sc = rstd * gamma[t];
    s_sc[t] = sc; s_sf[t] = beta[t] - mu*sc;
  }
  __syncthreads();
  int r0 = gstart[g], r1 = gstart[g+1];
  int q = t & 15, rr = t >> 4;   // 16 row-groups x 16 feature-slices
  float acc[8] = {0,0,0,0,0,0,0,0};
  for(int n = r0 + rr; n < r1; n += 16){
    uint4 u = ((const uint4*)raw)[(size_t)n*16 + q];
    acc[0] += fmaxf(fmaf(bflo(u.x), s_sc[q*8+0], s_sf[q*8+0]), 0.f);
    acc[1] += fmaxf(fmaf(bfhi(u.x), s_sc[q*8+1], s_sf[q*8+1]), 0.f);
    acc[2] += fmaxf(fmaf(bflo(u.y), s_sc[q*8+2], s_sf[q*8+2]), 0.f);
    acc[3] += fmaxf(fmaf(bfhi(u.y), s_sc[q*8+3], s_sf[q*8+3]), 0.f);
    acc[4] += fmaxf(fmaf(bflo(u.z), s_sc[q*8+4], s_sf[q*8+4]), 0.f);
    acc[5] += fmaxf(fmaf(bfhi(u.z), s_sc[q*8+5], s_sf[q*8+5]), 0.f);
    acc[6] += fmaxf(fmaf(bflo(u.w), s_sc[q*8+6], s_sf[q*8+6]), 0.f);
    acc[7] += fmaxf(fmaf(bfhi(u.w), s_sc[q*8+7], s_sf[q*8+7]), 0.f);
  }
  #pragma unroll
  for(int k=0;k<8;k++) red[rr][q*8+k] = acc[k];
  __syncthreads();
  if(t < HID){
    float s = 0.f;
    #pragma unroll
    for(int j=0;j<16;j++) s += red[j][t];
    float ic = 1.0f / fmaxf((float)(r1 - r0), 1.0f);
    p[t] = s * ic;
  }
  __syncthreads();
  if(t < 64){
    float z = fc1b[t];
    #pragma unroll 4
    for(int k=0;k<HID;k++) z += p[k]*fc1W[k*64 + t];
    z = fmaxf(z, 0.f);
    float v = z * fc2W[t];
    #pragma unroll
    for(int off=32; off>0; off>>=1) v += __shfl_down(v, off, 64);
    if(t==0) out[g] = 1.0f/(1.0f + expf(-(v + fc2b[0])));
  }
}

extern "C" void kernel_launch(void* const* d_in, const int* in_sizes, int n_in,
                              void* d_out, int out_size, void* d_ws, size_t ws_size,
                              hipStream_t stream){
  const float* x    = (const float*)d_in[0];
  const int*   ei   = (const int*)d_in[1];
  const int*   batch= (const int*)d_in[2];
  const float* Wn0=(const float*)d_in[3]; const float* Wr0=(const float*)d_in[4]; const float* b0=(const float*)d_in[5];
  const float* Wn1=(const float*)d_in[6]; const float* Wr1=(const float*)d_in[7]; const float* b1=(const float*)d_in[8];
  const float* Wn2=(const float*)d_in[9]; const float* Wr2=(const float*)d_in[10]; const float* b2=(const float*)d_in[11];
  const float* gamma=(const float*)d_in[12]; const float* beta=(const float*)d_in[13];
  const float* fc1W=(const float*)d_in[14]; const float* fc1b=(const float*)d_in[15];
  const float* fc2W=(const float*)d_in[16]; const float* fc2b=(const float*)d_in[17];
  float* out = (float*)d_out;

  char* ws = (char*)d_ws;
  size_t off = 0;
  auto alloc = [&](size_t bytes)->char*{ char* p = ws + off; off += (bytes + 255) & ~(size_t)255; return p; };

  // --- zeroed region (single memset): bcount | bfill | pstats ---
  char* zero0   = ws + off;
  int*   bcount = (int*)alloc((size_t)NB*4);
  int*   bfill  = (int*)alloc((size_t)NB*4);
  float* pstats = (float*)alloc((size_t)3*2*SPREAD*HID*4);
  size_t zbytes = (size_t)((ws + off) - zero0);

  // --- non-zeroed scratch ---
  unsigned short* H0  = (unsigned short*)alloc((size_t)N_NODES*IN_DIM*2);
  unsigned short* H1  = (unsigned short*)alloc((size_t)N_NODES*HID*2);
  unsigned short* H2  = (unsigned short*)alloc((size_t)N_NODES*HID*2);
  unsigned short* raw = (unsigned short*)alloc((size_t)N_NODES*HID*2);
  unsigned short* Bp0 = (unsigned short*)alloc((size_t)8*4*64*8*2);
  unsigned short* Bp1 = (unsigned short*)alloc((size_t)8*8*64*8*2);
  unsigned short* Bp2 = (unsigned short*)alloc((size_t)8*8*64*8*2);
  float* invdeg = (float*)alloc((size_t)N_NODES*4);
  int* rowptr   = (int*)alloc((size_t)(N_NODES+1)*4);
  unsigned short* eidx = (unsigned short*)alloc((size_t)N_EDGES*2);
  unsigned* pairs = (unsigned*)alloc((size_t)N_EDGES*4);
  int* gstart   = (int*)alloc((size_t)(NUM_GRAPHS+1)*4);

  auto psumL = [&](int l){ return pstats + (size_t)l*2*SPREAD*HID; };
  auto psqL  = [&](int l){ return pstats + (size_t)l*2*SPREAD*HID + (size_t)SPREAD*HID; };

  const int* src = ei;
  const int* dst = ei + N_EDGES;

  hipMemsetAsync(zero0, 0, zbytes, stream);

  // CSR build + packs + graph bounds (ride along with scatter dispatch)
  k_hist<<<NCHUNK, 256, 0, stream>>>(dst, bcount);
  k_scatter_pack<<<NCHUNK+PX_BLKS+W0_BLKS+2*W1_BLKS+GB_BLKS, 256, 0, stream>>>(src, dst, bcount, bfill, pairs,
      x, H0, Wn0, Wr0, Bp0, Wn1, Wr1, Bp1, Wn2, Wr2, Bp2, batch, gstart);
  k_csr<<<NB, 1024, 0, stream>>>(pairs, bcount, rowptr, invdeg, eidx);

  const int AG_BLKS = (N_NODES + 31)/32;   // 1563

  // ---- layer 0 ----
  k_agg_gemm<IN_DIM><<<AG_BLKS, 256, 0, stream>>>(H0, eidx, rowptr, invdeg, Bp0, b0, raw, psumL(0), psqL(0));
  k_transform<<<(N_NODES*16)/256, 256, 0, stream>>>(raw, psumL(0), psqL(0), gamma+0*HID, beta+0*HID, H1);
  // ---- layer 1 ----
  k_agg_gemm<HID><<<AG_BLKS, 256, 0, stream>>>(H1, eidx, rowptr, invdeg, Bp1, b1, raw, psumL(1), psqL(1));
  k_transform<<<(N_NODES*16)/256, 256, 0, stream>>>(raw, psumL(1), psqL(1), gamma+1*HID, beta+1*HID, H2);
  // ---- layer 2 ----
  k_agg_gemm<HID><<<AG_BLKS, 256, 0, stream>>>(H2, eidx, rowptr, invdeg, Bp2, b2, raw, psumL(2), psqL(2));

  // ---- fused pool + BN2 + ReLU + MLP head (one block per graph, no atomics) ----
  k_poolmlp<<<NUM_GRAPHS, 256, 0, stream>>>(raw, gstart, psumL(2), psqL(2), gamma+2*HID, beta+2*HID,
      fc1W, fc1b, fc2W, fc2b, out);
}

// Round 7
// 278.916 us; speedup vs baseline: 1.1863x; 1.0068x over previous
//
#include <hip/hip_runtime.h>

#define N_NODES 50000
#define N_EDGES 800000
#define NUM_GRAPHS 256
#define HID 128
#define IN_DIM 64
#define BN_EPS 1e-5f
#define SPREAD 16
#define NB 196            // buckets: dst>>8
#define BUCKET 256        // nodes per bucket
#define SCHUNK 4096       // edges per scatter block
#define NCHUNK 196        // ceil(N_EDGES/SCHUNK)
#define PX_BLKS 1563      // ceil(N_NODES*8/256)
#define W0_BLKS 8         // 8*4*64/256
#define W1_BLKS 16        // 8*8*64/256
#define GB_BLKS 196       // ceil(N_NODES/256) graph-boundary blocks

typedef __attribute__((ext_vector_type(8))) short bf16x8;
typedef __attribute__((ext_vector_type(4))) float f32x4;

// ---- bf16 helpers ----
__device__ __forceinline__ float bf2f(unsigned short u){ union{unsigned i;float f;}c; c.i=((unsigned)u)<<16; return c.f; }
__device__ __forceinline__ float bflo(unsigned w){ union{unsigned i;float f;}c; c.i=w<<16; return c.f; }
__device__ __forceinline__ float bfhi(unsigned w){ union{unsigned i;float f;}c; c.i=w&0xFFFF0000u; return c.f; }
__device__ __forceinline__ unsigned short f2bf(float f){ union{float f;unsigned i;}c; c.f=f; unsigned r=c.i+0x7FFF+((c.i>>16)&1); return (unsigned short)(r>>16); }
__device__ __forceinline__ unsigned fpack(float a, float b){
  union{float f;unsigned i;}ca,cb; ca.f=a; cb.f=b;
  unsigned ra=((ca.i+0x7FFF+((ca.i>>16)&1))>>16)&0xFFFFu;
  unsigned rb=(cb.i+0x7FFF+((cb.i>>16)&1))&0xFFFF0000u;
  return ra|rb;
}
__device__ __forceinline__ void acc8(float* a, uint4 u){
  a[0]+=bflo(u.x); a[1]+=bfhi(u.x); a[2]+=bflo(u.y); a[3]+=bfhi(u.y);
  a[4]+=bflo(u.z); a[5]+=bfhi(u.z); a[6]+=bflo(u.w); a[7]+=bfhi(u.w);
}

// ---------------- bucket histogram ----------------
__global__ __launch_bounds__(256) void k_hist(const int* __restrict__ dst, int* __restrict__ bcount){
  __shared__ int h[NB];
  int t = threadIdx.x;
  for(int i=t;i<NB;i+=256) h[i]=0;
  __syncthreads();
  int base = blockIdx.x*SCHUNK;
  int n = min(SCHUNK, N_EDGES-base);
  for(int v=t; v<n; v+=256) atomicAdd(&h[dst[base+v]>>8], 1);
  __syncthreads();
  for(int i=t;i<NB;i+=256) if(h[i]) atomicAdd(&bcount[i], h[i]);
}

// ---------------- fused: LDS-staged bucket scatter + packX + packW x3 + graph bounds ----------------
__global__ __launch_bounds__(256) void k_scatter_pack(const int* __restrict__ src, const int* __restrict__ dst,
      const int* __restrict__ bcount, int* __restrict__ bfill, unsigned* __restrict__ pairs,
      const float* __restrict__ x, unsigned short* __restrict__ H0,
      const float* __restrict__ Wn0, const float* __restrict__ Wr0, unsigned short* __restrict__ Bp0,
      const float* __restrict__ Wn1, const float* __restrict__ Wr1, unsigned short* __restrict__ Bp1,
      const float* __restrict__ Wn2, const float* __restrict__ Wr2, unsigned short* __restrict__ Bp2,
      const int* __restrict__ batch, int* __restrict__ gstart){
  __shared__ int h[NB], lbase[NB], gbase[NB], cur[NB];
  __shared__ int sc[256];
  __shared__ unsigned staged[SCHUNK];
  int blk = blockIdx.x, t = threadIdx.x;
  if(blk < NCHUNK){
    for(int i=t;i<NB;i+=256) h[i]=0;
    __syncthreads();
    int base = blk*SCHUNK;
    int n = min(SCHUNK, N_EDGES-base);
    for(int v=t; v<n; v+=256) atomicAdd(&h[dst[base+v]>>8], 1);
    __syncthreads();
    int bc = (t<NB)? bcount[t] : 0;
    sc[t]=bc; __syncthreads();
    for(int off=1;off<256;off<<=1){ int u=(t>=off)?sc[t-off]:0; __syncthreads(); sc[t]+=u; __syncthreads(); }
    int bb_t = sc[t]-bc;
    __syncthreads();
    int hv = (t<NB)? h[t] : 0;
    sc[t]=hv; __syncthreads();
    for(int off=1;off<256;off<<=1){ int u=(t>=off)?sc[t-off]:0; __syncthreads(); sc[t]+=u; __syncthreads(); }
    if(t<NB){ lbase[t]=sc[t]-hv; cur[t]=0; if(hv) gbase[t] = bb_t + atomicAdd(&bfill[t], hv); }
    __syncthreads();
    for(int v=t; v<n; v+=256){
      int s = src[base+v], d = dst[base+v];
      int b = d>>8;
      int rr = atomicAdd(&cur[b], 1);
      staged[lbase[b]+rr] = (unsigned)s | ((unsigned)(d&255)<<16) | ((unsigned)b<<24);
    }
    __syncthreads();
    for(int i=t; i<n; i+=256){
      unsigned p = staged[i];
      int b = (int)(p>>24);
      pairs[gbase[b] + (i - lbase[b])] = p;
    }
  } else if(blk < NCHUNK+PX_BLKS){
    int tid = (blk-NCHUNK)*256 + t;        // N_NODES*8 units of 8 feats
    if(tid < N_NODES*8){
      int row = tid>>3, q = tid&7;
      float4 a = ((const float4*)x)[(size_t)row*16 + q*2];
      float4 b = ((const float4*)x)[(size_t)row*16 + q*2 + 1];
      uint4 o;
      o.x = fpack(a.x,a.y); o.y = fpack(a.z,a.w);
      o.z = fpack(b.x,b.y); o.w = fpack(b.z,b.w);
      ((uint4*)H0)[(size_t)row*8 + q] = o;
    }
  } else if(blk < NCHUNK+PX_BLKS+W0_BLKS+2*W1_BLKS){
    const float *Wn, *Wr; unsigned short* Bp; int KH, base;
    if(blk < NCHUNK+PX_BLKS+W0_BLKS){ Wn=Wn0; Wr=Wr0; Bp=Bp0; KH=IN_DIM; base=NCHUNK+PX_BLKS; }
    else if(blk < NCHUNK+PX_BLKS+W0_BLKS+W1_BLKS){ Wn=Wn1; Wr=Wr1; Bp=Bp1; KH=HID; base=NCHUNK+PX_BLKS+W0_BLKS; }
    else { Wn=Wn2; Wr=Wr2; Bp=Bp2; KH=HID; base=NCHUNK+PX_BLKS+W0_BLKS+W1_BLKS; }
    int NKS = (2*KH)/32;
    int id = (blk-base)*256 + t;
    if(id < 8*NKS*64){
      int lane = id & 63;
      int ks = (id>>6) % NKS;
      int nt = (id>>6) / NKS;
      int quad = lane>>4, m = lane&15;
      int c = nt*16 + m;
      unsigned short v[8];
      #pragma unroll
      for(int j=0;j<8;j++){
        int k = ks*32 + quad*8 + j;
        float w = (k < KH) ? Wn[(size_t)k*HID + c] : Wr[(size_t)(k-KH)*HID + c];
        v[j] = f2bf(w);
      }
      uint4 o;
      o.x = ((unsigned)v[1]<<16)|v[0]; o.y = ((unsigned)v[3]<<16)|v[2];
      o.z = ((unsigned)v[5]<<16)|v[4]; o.w = ((unsigned)v[7]<<16)|v[6];
      ((uint4*)Bp)[id] = o;
    }
  } else {
    // graph boundary detection: gstart[g] = first node index with batch >= g (batch sorted)
    int id = (blk - (NCHUNK+PX_BLKS+W0_BLKS+2*W1_BLKS))*256 + t;
    if(id < N_NODES){
      int b = batch[id];
      if(id == 0){
        for(int g=0; g<=b; g++) gstart[g] = 0;
      } else {
        int pv = batch[id-1];
        if(pv != b) for(int g=pv+1; g<=b; g++) gstart[g] = id;
      }
      if(id == N_NODES-1){
        for(int g=b+1; g<=NUM_GRAPHS; g++) gstart[g] = N_NODES;
      }
    }
  }
}

// ---------------- per-bucket exact CSR (eidx as u16) ----------------
__global__ __launch_bounds__(1024) void k_csr(const unsigned* __restrict__ pairs, const int* __restrict__ bcount,
                int* __restrict__ rowptr, float* __restrict__ invdeg, unsigned short* __restrict__ eidx){
  __shared__ int cnt[BUCKET], cur[BUCKET], sc[BUCKET];
  __shared__ int bb[2];
  int t = threadIdx.x;
  int b = blockIdx.x;
  if(t==0){ bb[0]=0; bb[1]=0; }
  if(t<BUCKET) cnt[t]=0;
  __syncthreads();
  if(t<NB){
    int c = bcount[t];
    if(t<b)  atomicAdd(&bb[0], c);
    if(t<=b) atomicAdd(&bb[1], c);
  }
  __syncthreads();
  int e0 = bb[0], e1 = bb[1];
  int node0 = b*BUCKET;
  for(int i=e0+t; i<e1; i+=1024) atomicAdd(&cnt[(int)((pairs[i]>>16)&0xFF)], 1);
  __syncthreads();
  if(t<BUCKET) sc[t]=cnt[t];
  __syncthreads();
  for(int off=1;off<BUCKET;off<<=1){
    int u=0;
    if(t<BUCKET && t>=off) u=sc[t-off];
    __syncthreads();
    if(t<BUCKET) sc[t]+=u;
    __syncthreads();
  }
  if(t<BUCKET && node0+t < N_NODES){
    int pre = sc[t]-cnt[t] + e0;
    rowptr[node0+t] = pre;
    cur[t] = pre;
    invdeg[node0+t] = 1.0f/(float)max(cnt[t],1);
  }
  if(b==0 && t==0) rowptr[N_NODES] = N_EDGES;
  __syncthreads();
  for(int i=e0+t; i<e1; i+=1024){
    unsigned p = pairs[i];
    int pos = atomicAdd(&cur[(p>>16)&0xFF], 1);
    eidx[pos] = (unsigned short)(p & 0xFFFF);
  }
}

// ---------------- FUSED: mean-aggregate + MFMA GEMM + col-stats, max-TLP ----------------
// 16 rows per block, 4 waves, 3125 blocks (12.2 blocks/CU). Gather: each wave aggregates
// only 4 rows into shared LDS (4 serial node-gathers). One barrier. GEMM: each wave owns
// all 16 rows x 32 cols (wave = col strip), 2 accumulators.
template<int KH>   // 64 or 128; K = 2*KH
__global__ __launch_bounds__(256) void k_agg_gemm(const unsigned short* __restrict__ H,
                     const unsigned short* __restrict__ eidx, const int* __restrict__ rowptr,
                     const float* __restrict__ invdeg,
                     const unsigned short* __restrict__ Bp, const float* __restrict__ bias,
                     unsigned short* __restrict__ raw,
                     float* __restrict__ psum, float* __restrict__ psq){
  const int NKS = (2*KH)/32;
  const int LKS = KH/32;
  const int F8  = KH/8;    // lanes per row-slice: 8 / 16
  const int RPI = 64/F8;   // rows (edges) in flight per wave-iter: 8 / 4
  const int LDA = KH + 4;  // +4 ushort pad: conflict-free frag reads
  __shared__ unsigned short Alds[16*LDA];
  int wave = threadIdx.x>>6, lane = threadIdx.x&63;
  int row0b = blockIdx.x*16;   // 3125*16 == N_NODES exactly

  // ---- gather phase: wave aggregates 4 rows into LDS ----
  int r = lane / F8, q = lane % F8;
  #pragma unroll
  for(int j=0; j<4; j++){
    int li = wave*4 + j;           // row within block
    int n = row0b + li;
    int b = rowptr[n], e = rowptr[n+1];
    float acc[8] = {0,0,0,0,0,0,0,0};
    int i = b + r;
    for(; i + 3*RPI < e; i += 4*RPI){
      int s0 = eidx[i], s1 = eidx[i+RPI], s2 = eidx[i+2*RPI], s3 = eidx[i+3*RPI];
      uint4 u0 = *(const uint4*)(H + (size_t)s0*KH + q*8);
      uint4 u1 = *(const uint4*)(H + (size_t)s1*KH + q*8);
      uint4 u2 = *(const uint4*)(H + (size_t)s2*KH + q*8);
      uint4 u3 = *(const uint4*)(H + (size_t)s3*KH + q*8);
      acc8(acc,u0); acc8(acc,u1); acc8(acc,u2); acc8(acc,u3);
    }
    for(; i + RPI < e; i += 2*RPI){
      int s0 = eidx[i], s1 = eidx[i+RPI];
      uint4 u0 = *(const uint4*)(H + (size_t)s0*KH + q*8);
      uint4 u1 = *(const uint4*)(H + (size_t)s1*KH + q*8);
      acc8(acc,u0); acc8(acc,u1);
    }
    for(; i < e; i += RPI){
      int s0 = eidx[i];
      uint4 u0 = *(const uint4*)(H + (size_t)s0*KH + q*8);
      acc8(acc,u0);
    }
    #pragma unroll
    for(int off = F8; off < 64; off <<= 1){
      #pragma unroll
      for(int k=0;k<8;k++) acc[k] += __shfl_xor(acc[k], off, 64);
    }
    if(lane < F8){
      float id = invdeg[n];
      uint4 o;
      o.x = fpack(acc[0]*id, acc[1]*id); o.y = fpack(acc[2]*id, acc[3]*id);
      o.z = fpack(acc[4]*id, acc[5]*id); o.w = fpack(acc[6]*id, acc[7]*id);
      *(uint4*)(Alds + li*LDA + lane*8) = o;
    }
  }
  __syncthreads();

  // ---- GEMM phase: wave tile = 16 rows (all) x 32 cols (wave strip) ----
  int m = lane&15, quad = lane>>4;
  const unsigned short* Arow = Alds + m*LDA + quad*8;
  const unsigned short* Hrow = H + (size_t)(row0b+m)*KH + quad*8;
  f32x4 facc[2];
  facc[0] = (f32x4){0.f,0.f,0.f,0.f};
  facc[1] = (f32x4){0.f,0.f,0.f,0.f};
  #pragma unroll 1
  for(int ks=0; ks<NKS; ks++){
    bf16x8 a = (ks < LKS) ? *(const bf16x8*)(Arow + ks*32)
                          : *(const bf16x8*)(Hrow + (size_t)(ks-LKS)*32);
    const unsigned short* bp = Bp + (((size_t)(wave*2)*NKS + ks)*64 + lane)*8;
    bf16x8 b0 = *(const bf16x8*)(bp);
    bf16x8 b1 = *(const bf16x8*)(bp + (size_t)NKS*64*8);
    facc[0] = __builtin_amdgcn_mfma_f32_16x16x32_bf16(a, b0, facc[0], 0, 0, 0);
    facc[1] = __builtin_amdgcn_mfma_f32_16x16x32_bf16(a, b1, facc[1], 0, 0, 0);
  }
  int sp = blockIdx.x & (SPREAD-1);
  #pragma unroll
  for(int nt=0;nt<2;nt++){
    int col = wave*32 + nt*16 + m;
    float bv = bias[col];
    float s = 0.f, s2 = 0.f;
    #pragma unroll
    for(int reg=0;reg<4;reg++){
      float v = facc[nt][reg] + bv;
      int row = row0b + quad*4 + reg;
      raw[(size_t)row*HID + col] = f2bf(v);
      s += v; s2 += v*v;
    }
    s  += __shfl_xor(s, 16, 64);  s  += __shfl_xor(s, 32, 64);
    s2 += __shfl_xor(s2, 16, 64); s2 += __shfl_xor(s2, 32, 64);
    if(quad==0){
      atomicAdd(&psum[sp*HID+col], s);
      atomicAdd(&psq [sp*HID+col], s2);
    }
  }
}

// ---------------- BN+ReLU transform (inline stats reduce): raw -> H_next ----------------
__global__ __launch_bounds__(256) void k_transform(const unsigned short* __restrict__ raw,
      const float* __restrict__ psum, const float* __restrict__ psq,
      const float* __restrict__ gamma, const float* __restrict__ beta,
      unsigned short* __restrict__ Hout){
  __shared__ float s_sc[HID], s_sf[HID];
  int t = threadIdx.x;
  if(t < HID){
    float s=0.f, s2=0.f;
    #pragma unroll
    for(int i=0;i<SPREAD;i++){ s += psum[i*HID+t]; s2 += psq[i*HID+t]; }
    float mu  = s  * (1.0f/(float)N_NODES);
    float var = s2 * (1.0f/(float)N_NODES) - mu*mu;
    float rstd = rsqrtf(var + BN_EPS);
    float sc = rstd * gamma[t];
    s_sc[t] = sc; s_sf[t] = beta[t] - mu*sc;
  }
  __syncthreads();
  int tid = blockIdx.x*256 + t;   // N_NODES*16 uint4 units
  if(tid >= N_NODES*16) return;
  int q = tid & 15;
  uint4 u = ((const uint4*)raw)[tid];
  float f0 = fmaxf(fmaf(bflo(u.x), s_sc[q*8+0], s_sf[q*8+0]), 0.f);
  float f1 = fmaxf(fmaf(bfhi(u.x), s_sc[q*8+1], s_sf[q*8+1]), 0.f);
  float f2 = fmaxf(fmaf(bflo(u.y), s_sc[q*8+2], s_sf[q*8+2]), 0.f);
  float f3 = fmaxf(fmaf(bfhi(u.y), s_sc[q*8+3], s_sf[q*8+3]), 0.f);
  float f4 = fmaxf(fmaf(bflo(u.z), s_sc[q*8+4], s_sf[q*8+4]), 0.f);
  float f5 = fmaxf(fmaf(bfhi(u.z), s_sc[q*8+5], s_sf[q*8+5]), 0.f);
  float f6 = fmaxf(fmaf(bflo(u.w), s_sc[q*8+6], s_sf[q*8+6]), 0.f);
  float f7 = fmaxf(fmaf(bfhi(u.w), s_sc[q*8+7], s_sf[q*8+7]), 0.f);
  uint4 o;
  o.x = fpack(f0,f1); o.y = fpack(f2,f3); o.z = fpack(f4,f5); o.w = fpack(f6,f7);
  ((uint4*)Hout)[tid] = o;
}

// ---------------- FUSED: global mean pool (one block per graph, no atomics) + BN2 + ReLU + MLP head ----------------
__global__ __launch_bounds__(256) void k_poolmlp(const unsigned short* __restrict__ raw,
      const int* __restrict__ gstart,
      const float* __restrict__ psum, const float* __restrict__ psq,
      const float* __restrict__ gamma, const float* __restrict__ beta,
      const float* __restrict__ fc1W, const float* __restrict__ fc1b,
      const float* __restrict__ fc2W, const float* __restrict__ fc2b,
      float* __restrict__ out){
  __shared__ float s_sc[HID], s_sf[HID];
  __shared__ float red[16][HID];
  __shared__ float p[HID];
  int g = blockIdx.x, t = threadIdx.x;
  if(t < HID){
    float s=0.f, s2=0.f;
    #pragma unroll
    for(int i=0;i<SPREAD;i++){ s += psum[i*HID+t]; s2 += psq[i*HID+t]; }
    float mu  = s  * (1.0f/(float)N_NODES);
    float var = s2 * (1.0f/(float)N_NODES) - mu*mu;
    float rstd = rsqrtf(var + BN_EPS);
    float sc = rstd * gamma[t];
    s_sc[t] = sc; s_sf[t] = beta[t] - mu*sc;
  }
  __syncthreads();
  int r0 = gstart[g], r1 = gstart[g+1];
  int q = t & 15, rr = t >> 4;   // 16 row-groups x 16 feature-slices
  float acc[8] = {0,0,0,0,0,0,0,0};
  for(int n = r0 + rr; n < r1; n += 16){
    uint4 u = ((const uint4*)raw)[(size_t)n*16 + q];
    acc[0] += fmaxf(fmaf(bflo(u.x), s_sc[q*8+0], s_sf[q*8+0]), 0.f);
    acc[1] += fmaxf(fmaf(bfhi(u.x), s_sc[q*8+1], s_sf[q*8+1]), 0.f);
    acc[2] += fmaxf(fmaf(bflo(u.y), s_sc[q*8+2], s_sf[q*8+2]), 0.f);
    acc[3] += fmaxf(fmaf(bfhi(u.y), s_sc[q*8+3], s_sf[q*8+3]), 0.f);
    acc[4] += fmaxf(fmaf(bflo(u.z), s_sc[q*8+4], s_sf[q*8+4]), 0.f);
    acc[5] += fmaxf(fmaf(bfhi(u.z), s_sc[q*8+5], s_sf[q*8+5]), 0.f);
    acc[6] += fmaxf(fmaf(bflo(u.w), s_sc[q*8+6], s_sf[q*8+6]), 0.f);
    acc[7] += fmaxf(fmaf(bfhi(u.w), s_sc[q*8+7], s_sf[q*8+7]), 0.f);
  }
  #pragma unroll
  for(int k=0;k<8;k++) red[rr][q*8+k] = acc[k];
  __syncthreads();
  if(t < HID){
    float s = 0.f;
    #pragma unroll
    for(int j=0;j<16;j++) s += red[j][t];
    float ic = 1.0f / fmaxf((float)(r1 - r0), 1.0f);
    p[t] = s * ic;
  }
  __syncthreads();
  if(t < 64){
    float z = fc1b[t];
    #pragma unroll 4
    for(int k=0;k<HID;k++) z += p[k]*fc1W[k*64 + t];
    z = fmaxf(z, 0.f);
    float v = z * fc2W[t];
    #pragma unroll
    for(int off=32; off>0; off>>=1) v += __shfl_down(v, off, 64);
    if(t==0) out[g] = 1.0f/(1.0f + expf(-(v + fc2b[0])));
  }
}

extern "C" void kernel_launch(void* const* d_in, const int* in_sizes, int n_in,
                              void* d_out, int out_size, void* d_ws, size_t ws_size,
                              hipStream_t stream){
  const float* x    = (const float*)d_in[0];
  const int*   ei   = (const int*)d_in[1];
  const int*   batch= (const int*)d_in[2];
  const float* Wn0=(const float*)d_in[3]; const float* Wr0=(const float*)d_in[4]; const float* b0=(const float*)d_in[5];
  const float* Wn1=(const float*)d_in[6]; const float* Wr1=(const float*)d_in[7]; const float* b1=(const float*)d_in[8];
  const float* Wn2=(const float*)d_in[9]; const float* Wr2=(const float*)d_in[10]; const float* b2=(const float*)d_in[11];
  const float* gamma=(const float*)d_in[12]; const float* beta=(const float*)d_in[13];
  const float* fc1W=(const float*)d_in[14]; const float* fc1b=(const float*)d_in[15];
  const float* fc2W=(const float*)d_in[16]; const float* fc2b=(const float*)d_in[17];
  float* out = (float*)d_out;

  char* ws = (char*)d_ws;
  size_t off = 0;
  auto alloc = [&](size_t bytes)->char*{ char* p = ws + off; off += (bytes + 255) & ~(size_t)255; return p; };

  // --- zeroed region (single memset): bcount | bfill | pstats ---
  char* zero0   = ws + off;
  int*   bcount = (int*)alloc((size_t)NB*4);
  int*   bfill  = (int*)alloc((size_t)NB*4);
  float* pstats = (float*)alloc((size_t)3*2*SPREAD*HID*4);
  size_t zbytes = (size_t)((ws + off) - zero0);

  // --- non-zeroed scratch ---
  unsigned short* H0  = (unsigned short*)alloc((size_t)N_NODES*IN_DIM*2);
  unsigned short* H1  = (unsigned short*)alloc((size_t)N_NODES*HID*2);
  unsigned short* H2  = (unsigned short*)alloc((size_t)N_NODES*HID*2);
  unsigned short* raw = (unsigned short*)alloc((size_t)N_NODES*HID*2);
  unsigned short* Bp0 = (unsigned short*)alloc((size_t)8*4*64*8*2);
  unsigned short* Bp1 = (unsigned short*)alloc((size_t)8*8*64*8*2);
  unsigned short* Bp2 = (unsigned short*)alloc((size_t)8*8*64*8*2);
  float* invdeg = (float*)alloc((size_t)N_NODES*4);
  int* rowptr   = (int*)alloc((size_t)(N_NODES+1)*4);
  unsigned short* eidx = (unsigned short*)alloc((size_t)N_EDGES*2);
  unsigned* pairs = (unsigned*)alloc((size_t)N_EDGES*4);
  int* gstart   = (int*)alloc((size_t)(NUM_GRAPHS+1)*4);

  auto psumL = [&](int l){ return pstats + (size_t)l*2*SPREAD*HID; };
  auto psqL  = [&](int l){ return pstats + (size_t)l*2*SPREAD*HID + (size_t)SPREAD*HID; };

  const int* src = ei;
  const int* dst = ei + N_EDGES;

  hipMemsetAsync(zero0, 0, zbytes, stream);

  // CSR build + packs + graph bounds (ride along with scatter dispatch)
  k_hist<<<NCHUNK, 256, 0, stream>>>(dst, bcount);
  k_scatter_pack<<<NCHUNK+PX_BLKS+W0_BLKS+2*W1_BLKS+GB_BLKS, 256, 0, stream>>>(src, dst, bcount, bfill, pairs,
      x, H0, Wn0, Wr0, Bp0, Wn1, Wr1, Bp1, Wn2, Wr2, Bp2, batch, gstart);
  k_csr<<<NB, 1024, 0, stream>>>(pairs, bcount, rowptr, invdeg, eidx);

  const int AG_BLKS = (N_NODES + 15)/16;   // 3125

  // ---- layer 0 ----
  k_agg_gemm<IN_DIM><<<AG_BLKS, 256, 0, stream>>>(H0, eidx, rowptr, invdeg, Bp0, b0, raw, psumL(0), psqL(0));
  k_transform<<<(N_NODES*16)/256, 256, 0, stream>>>(raw, psumL(0), psqL(0), gamma+0*HID, beta+0*HID, H1);
  // ---- layer 1 ----
  k_agg_gemm<HID><<<AG_BLKS, 256, 0, stream>>>(H1, eidx, rowptr, invdeg, Bp1, b1, raw, psumL(1), psqL(1));
  k_transform<<<(N_NODES*16)/256, 256, 0, stream>>>(raw, psumL(1), psqL(1), gamma+1*HID, beta+1*HID, H2);
  // ---- layer 2 ----
  k_agg_gemm<HID><<<AG_BLKS, 256, 0, stream>>>(H2, eidx, rowptr, invdeg, Bp2, b2, raw, psumL(2), psqL(2));

  // ---- fused pool + BN2 + ReLU + MLP head (one block per graph, no atomics) ----
  k_poolmlp<<<NUM_GRAPHS, 256, 0, stream>>>(raw, gstart, psumL(2), psqL(2), gamma+2*HID, beta+2*HID,
      fc1W, fc1b, fc2W, fc2b, out);
}

// Round 9
// 263.661 us; speedup vs baseline: 1.2549x; 1.0579x over previous
//
#include <hip/hip_runtime.h>

#define N_NODES 50000
#define N_EDGES 800000
#define NUM_GRAPHS 256
#define HID 128
#define IN_DIM 64
#define BN_EPS 1e-5f
#define SPREAD 16
#define NB 196            // buckets: dst>>8
#define BUCKET 256        // nodes per bucket
#define SCHUNK 4096       // edges per scatter block
#define NCHUNK 196        // ceil(N_EDGES/SCHUNK)
#define PX_BLKS 1563      // ceil(N_NODES*8/256)
#define W0_BLKS 8         // 8*4*64/256
#define W1_BLKS 16        // 8*8*64/256
#define GB_BLKS 196       // ceil(N_NODES/256) graph-boundary blocks

typedef __attribute__((ext_vector_type(8))) short bf16x8;
typedef __attribute__((ext_vector_type(4))) float f32x4;

// ---- bf16 helpers ----
__device__ __forceinline__ float bf2f(unsigned short u){ union{unsigned i;float f;}c; c.i=((unsigned)u)<<16; return c.f; }
__device__ __forceinline__ float bflo(unsigned w){ union{unsigned i;float f;}c; c.i=w<<16; return c.f; }
__device__ __forceinline__ float bfhi(unsigned w){ union{unsigned i;float f;}c; c.i=w&0xFFFF0000u; return c.f; }
__device__ __forceinline__ unsigned short f2bf(float f){ union{float f;unsigned i;}c; c.f=f; unsigned r=c.i+0x7FFF+((c.i>>16)&1); return (unsigned short)(r>>16); }
__device__ __forceinline__ unsigned fpack(float a, float b){
  union{float f;unsigned i;}ca,cb; ca.f=a; cb.f=b;
  unsigned ra=((ca.i+0x7FFF+((ca.i>>16)&1))>>16)&0xFFFFu;
  unsigned rb=(cb.i+0x7FFF+((cb.i>>16)&1))&0xFFFF0000u;
  return ra|rb;
}
__device__ __forceinline__ void acc8(float* a, uint4 u){
  a[0]+=bflo(u.x); a[1]+=bfhi(u.x); a[2]+=bflo(u.y); a[3]+=bfhi(u.y);
  a[4]+=bflo(u.z); a[5]+=bfhi(u.z); a[6]+=bflo(u.w); a[7]+=bfhi(u.w);
}

// ---------------- bucket histogram ----------------
__global__ __launch_bounds__(256) void k_hist(const int* __restrict__ dst, int* __restrict__ bcount){
  __shared__ int h[NB];
  int t = threadIdx.x;
  for(int i=t;i<NB;i+=256) h[i]=0;
  __syncthreads();
  int base = blockIdx.x*SCHUNK;
  int n = min(SCHUNK, N_EDGES-base);
  for(int v=t; v<n; v+=256) atomicAdd(&h[dst[base+v]>>8], 1);
  __syncthreads();
  for(int i=t;i<NB;i+=256) if(h[i]) atomicAdd(&bcount[i], h[i]);
}

// ---------------- fused: LDS-staged bucket scatter + packX + packW x3 + graph bounds ----------------
__global__ __launch_bounds__(256) void k_scatter_pack(const int* __restrict__ src, const int* __restrict__ dst,
      const int* __restrict__ bcount, int* __restrict__ bfill, unsigned* __restrict__ pairs,
      const float* __restrict__ x, unsigned short* __restrict__ H0,
      const float* __restrict__ Wn0, const float* __restrict__ Wr0, unsigned short* __restrict__ Bp0,
      const float* __restrict__ Wn1, const float* __restrict__ Wr1, unsigned short* __restrict__ Bp1,
      const float* __restrict__ Wn2, const float* __restrict__ Wr2, unsigned short* __restrict__ Bp2,
      const int* __restrict__ batch, int* __restrict__ gstart){
  __shared__ int h[NB], lbase[NB], gbase[NB], cur[NB];
  __shared__ int sc[256];
  __shared__ unsigned staged[SCHUNK];
  int blk = blockIdx.x, t = threadIdx.x;
  if(blk < NCHUNK){
    for(int i=t;i<NB;i+=256) h[i]=0;
    __syncthreads();
    int base = blk*SCHUNK;
    int n = min(SCHUNK, N_EDGES-base);
    for(int v=t; v<n; v+=256) atomicAdd(&h[dst[base+v]>>8], 1);
    __syncthreads();
    int bc = (t<NB)? bcount[t] : 0;
    sc[t]=bc; __syncthreads();
    for(int off=1;off<256;off<<=1){ int u=(t>=off)?sc[t-off]:0; __syncthreads(); sc[t]+=u; __syncthreads(); }
    int bb_t = sc[t]-bc;
    __syncthreads();
    int hv = (t<NB)? h[t] : 0;
    sc[t]=hv; __syncthreads();
    for(int off=1;off<256;off<<=1){ int u=(t>=off)?sc[t-off]:0; __syncthreads(); sc[t]+=u; __syncthreads(); }
    if(t<NB){ lbase[t]=sc[t]-hv; cur[t]=0; if(hv) gbase[t] = bb_t + atomicAdd(&bfill[t], hv); }
    __syncthreads();
    for(int v=t; v<n; v+=256){
      int s = src[base+v], d = dst[base+v];
      int b = d>>8;
      int rr = atomicAdd(&cur[b], 1);
      staged[lbase[b]+rr] = (unsigned)s | ((unsigned)(d&255)<<16) | ((unsigned)b<<24);
    }
    __syncthreads();
    for(int i=t; i<n; i+=256){
      unsigned p = staged[i];
      int b = (int)(p>>24);
      pairs[gbase[b] + (i - lbase[b])] = p;
    }
  } else if(blk < NCHUNK+PX_BLKS){
    int tid = (blk-NCHUNK)*256 + t;        // N_NODES*8 units of 8 feats
    if(tid < N_NODES*8){
      int row = tid>>3, q = tid&7;
      float4 a = ((const float4*)x)[(size_t)row*16 + q*2];
      float4 b = ((const float4*)x)[(size_t)row*16 + q*2 + 1];
      uint4 o;
      o.x = fpack(a.x,a.y); o.y = fpack(a.z,a.w);
      o.z = fpack(b.x,b.y); o.w = fpack(b.z,b.w);
      ((uint4*)H0)[(size_t)row*8 + q] = o;
    }
  } else if(blk < NCHUNK+PX_BLKS+W0_BLKS+2*W1_BLKS){
    const float *Wn, *Wr; unsigned short* Bp; int KH, base;
    if(blk < NCHUNK+PX_BLKS+W0_BLKS){ Wn=Wn0; Wr=Wr0; Bp=Bp0; KH=IN_DIM; base=NCHUNK+PX_BLKS; }
    else if(blk < NCHUNK+PX_BLKS+W0_BLKS+W1_BLKS){ Wn=Wn1; Wr=Wr1; Bp=Bp1; KH=HID; base=NCHUNK+PX_BLKS+W0_BLKS; }
    else { Wn=Wn2; Wr=Wr2; Bp=Bp2; KH=HID; base=NCHUNK+PX_BLKS+W0_BLKS+W1_BLKS; }
    int NKS = (2*KH)/32;
    int id = (blk-base)*256 + t;
    if(id < 8*NKS*64){
      int lane = id & 63;
      int ks = (id>>6) % NKS;
      int nt = (id>>6) / NKS;
      int quad = lane>>4, m = lane&15;
      int c = nt*16 + m;
      unsigned short v[8];
      #pragma unroll
      for(int j=0;j<8;j++){
        int k = ks*32 + quad*8 + j;
        float w = (k < KH) ? Wn[(size_t)k*HID + c] : Wr[(size_t)(k-KH)*HID + c];
        v[j] = f2bf(w);
      }
      uint4 o;
      o.x = ((unsigned)v[1]<<16)|v[0]; o.y = ((unsigned)v[3]<<16)|v[2];
      o.z = ((unsigned)v[5]<<16)|v[4]; o.w = ((unsigned)v[7]<<16)|v[6];
      ((uint4*)Bp)[id] = o;
    }
  } else {
    // graph boundary detection: gstart[g] = first node index with batch >= g (batch sorted)
    int id = (blk - (NCHUNK+PX_BLKS+W0_BLKS+2*W1_BLKS))*256 + t;
    if(id < N_NODES){
      int b = batch[id];
      if(id == 0){
        for(int g=0; g<=b; g++) gstart[g] = 0;
      } else {
        int pv = batch[id-1];
        if(pv != b) for(int g=pv+1; g<=b; g++) gstart[g] = id;
      }
      if(id == N_NODES-1){
        for(int g=b+1; g<=NUM_GRAPHS; g++) gstart[g] = N_NODES;
      }
    }
  }
}

// ---------------- per-bucket exact CSR (eidx as u16) ----------------
__global__ __launch_bounds__(1024) void k_csr(const unsigned* __restrict__ pairs, const int* __restrict__ bcount,
                int* __restrict__ rowptr, float* __restrict__ invdeg, unsigned short* __restrict__ eidx){
  __shared__ int cnt[BUCKET], cur[BUCKET], sc[BUCKET];
  __shared__ int bb[2];
  int t = threadIdx.x;
  int b = blockIdx.x;
  if(t==0){ bb[0]=0; bb[1]=0; }
  if(t<BUCKET) cnt[t]=0;
  __syncthreads();
  if(t<NB){
    int c = bcount[t];
    if(t<b)  atomicAdd(&bb[0], c);
    if(t<=b) atomicAdd(&bb[1], c);
  }
  __syncthreads();
  int e0 = bb[0], e1 = bb[1];
  int node0 = b*BUCKET;
  for(int i=e0+t; i<e1; i+=1024) atomicAdd(&cnt[(int)((pairs[i]>>16)&0xFF)], 1);
  __syncthreads();
  if(t<BUCKET) sc[t]=cnt[t];
  __syncthreads();
  for(int off=1;off<BUCKET;off<<=1){
    int u=0;
    if(t<BUCKET && t>=off) u=sc[t-off];
    __syncthreads();
    if(t<BUCKET) sc[t]+=u;
    __syncthreads();
  }
  if(t<BUCKET && node0+t < N_NODES){
    int pre = sc[t]-cnt[t] + e0;
    rowptr[node0+t] = pre;
    cur[t] = pre;
    invdeg[node0+t] = 1.0f/(float)max(cnt[t],1);
  }
  if(b==0 && t==0) rowptr[N_NODES] = N_EDGES;
  __syncthreads();
  for(int i=e0+t; i<e1; i+=1024){
    unsigned p = pairs[i];
    int pos = atomicAdd(&cur[(p>>16)&0xFF], 1);
    eidx[pos] = (unsigned short)(p & 0xFFFF);
  }
}

// ---------------- FUSED: mean-aggregate + MFMA GEMM + col-stats, lane-parallel rows ----------------
// 16 rows per block, 4 waves, 3125 blocks. Gather re-mapped: lane -> (row rr=lane>>4, slice q).
// Each lane privately sums ALL of its row's edges for its 16B slice -> NO cross-lane reduce
// (KH=64: 2-way edge split + one shfl_xor(8)). Edge indices staged in LDS once per block.
// 8-deep load unroll -> 8 loads in flight per lane.
template<int KH>   // 64 or 128; K = 2*KH
__global__ __launch_bounds__(256) void k_agg_gemm(const unsigned short* __restrict__ H,
                     const unsigned short* __restrict__ eidx, const int* __restrict__ rowptr,
                     const float* __restrict__ invdeg,
                     const unsigned short* __restrict__ Bp, const float* __restrict__ bias,
                     unsigned short* __restrict__ raw,
                     float* __restrict__ psum, float* __restrict__ psq){
  const int NKS = (2*KH)/32;
  const int LKS = KH/32;
  const int F8  = KH/8;     // slices per row: 8 (KH=64) / 16 (KH=128)
  const int SPL = 16/F8;    // per-row edge split: 2 / 1
  const int LDA = KH + 4;   // +4 ushort pad: conflict-free frag reads
  const int EDGE_CAP = 512; // block edge budget (mean 256, sigma 16 -> +16 sigma safe; guarded anyway)
  __shared__ unsigned short Alds[16*LDA];
  __shared__ unsigned short Elds[EDGE_CAP];
  __shared__ int rp[17];
  int t = threadIdx.x;
  int wave = t>>6, lane = t&63;
  int row0b = blockIdx.x*16;   // 3125*16 == N_NODES exactly

  if(t < 17) rp[t] = rowptr[row0b + t];
  __syncthreads();
  int ebase = rp[0];
  int etot  = rp[16] - ebase;
  bool fits = (etot <= EDGE_CAP);
  if(fits){
    for(int i=t; i<etot; i+=256) Elds[i] = eidx[ebase + i];
  }
  __syncthreads();

  // lane mapping
  int rr = lane >> 4;                        // row within wave (0..3)
  int h  = (SPL==1) ? 0 : ((lane>>3)&1);     // edge-half for KH=64
  int q  = lane & (F8-1);                    // 16B feature slice
  int li = wave*4 + rr;                      // row within block
  int b = rp[li] - ebase, e = rp[li+1] - ebase;
  float acc[8] = {0,0,0,0,0,0,0,0};

#define LDH(s) (*(const uint4*)(H + (size_t)(s)*KH + q*8))
#define GBODY(FETCH) { \
    int i = b + h; \
    for(; i + 7*SPL < e; i += 8*SPL){ \
      int s0=FETCH(i), s1=FETCH(i+SPL), s2=FETCH(i+2*SPL), s3=FETCH(i+3*SPL), \
          s4=FETCH(i+4*SPL), s5=FETCH(i+5*SPL), s6=FETCH(i+6*SPL), s7=FETCH(i+7*SPL); \
      uint4 u0=LDH(s0),u1=LDH(s1),u2=LDH(s2),u3=LDH(s3),u4=LDH(s4),u5=LDH(s5),u6=LDH(s6),u7=LDH(s7); \
      acc8(acc,u0); acc8(acc,u1); acc8(acc,u2); acc8(acc,u3); \
      acc8(acc,u4); acc8(acc,u5); acc8(acc,u6); acc8(acc,u7); \
    } \
    for(; i + 3*SPL < e; i += 4*SPL){ \
      int s0=FETCH(i), s1=FETCH(i+SPL), s2=FETCH(i+2*SPL), s3=FETCH(i+3*SPL); \
      uint4 u0=LDH(s0),u1=LDH(s1),u2=LDH(s2),u3=LDH(s3); \
      acc8(acc,u0); acc8(acc,u1); acc8(acc,u2); acc8(acc,u3); \
    } \
    for(; i < e; i += SPL){ \
      int s0=FETCH(i); uint4 u0=LDH(s0); acc8(acc,u0); \
    } }
#define FL(i) ((int)Elds[(i)])
#define FG(i) ((int)eidx[ebase + (i)])
  if(fits){ GBODY(FL) } else { GBODY(FG) }
#undef FL
#undef FG
#undef GBODY
#undef LDH

  if(SPL==2){
    #pragma unroll
    for(int k=0;k<8;k++) acc[k] += __shfl_xor(acc[k], 8, 64);
  }
  if(h==0){
    float id = invdeg[row0b + li];
    uint4 o;
    o.x = fpack(acc[0]*id, acc[1]*id); o.y = fpack(acc[2]*id, acc[3]*id);
    o.z = fpack(acc[4]*id, acc[5]*id); o.w = fpack(acc[6]*id, acc[7]*id);
    *(uint4*)(Alds + li*LDA + q*8) = o;
  }
  __syncthreads();

  // ---- GEMM phase: wave tile = 16 rows (all) x 32 cols (wave strip) ----
  int m = lane&15, quad = lane>>4;
  const unsigned short* Arow = Alds + m*LDA + quad*8;
  const unsigned short* Hrow = H + (size_t)(row0b+m)*KH + quad*8;
  f32x4 facc[2];
  facc[0] = (f32x4){0.f,0.f,0.f,0.f};
  facc[1] = (f32x4){0.f,0.f,0.f,0.f};
  #pragma unroll 1
  for(int ks=0; ks<NKS; ks++){
    bf16x8 a = (ks < LKS) ? *(const bf16x8*)(Arow + ks*32)
                          : *(const bf16x8*)(Hrow + (size_t)(ks-LKS)*32);
    const unsigned short* bp = Bp + (((size_t)(wave*2)*NKS + ks)*64 + lane)*8;
    bf16x8 b0 = *(const bf16x8*)(bp);
    bf16x8 b1 = *(const bf16x8*)(bp + (size_t)NKS*64*8);
    facc[0] = __builtin_amdgcn_mfma_f32_16x16x32_bf16(a, b0, facc[0], 0, 0, 0);
    facc[1] = __builtin_amdgcn_mfma_f32_16x16x32_bf16(a, b1, facc[1], 0, 0, 0);
  }
  int sp = blockIdx.x & (SPREAD-1);
  #pragma unroll
  for(int nt=0;nt<2;nt++){
    int col = wave*32 + nt*16 + m;
    float bv = bias[col];
    float s = 0.f, s2 = 0.f;
    #pragma unroll
    for(int reg=0;reg<4;reg++){
      float v = facc[nt][reg] + bv;
      int row = row0b + quad*4 + reg;
      raw[(size_t)row*HID + col] = f2bf(v);
      s += v; s2 += v*v;
    }
    s  += __shfl_xor(s, 16, 64);  s  += __shfl_xor(s, 32, 64);
    s2 += __shfl_xor(s2, 16, 64); s2 += __shfl_xor(s2, 32, 64);
    if(quad==0){
      atomicAdd(&psum[sp*HID+col], s);
      atomicAdd(&psq [sp*HID+col], s2);
    }
  }
}

// ---------------- BN+ReLU transform (inline stats reduce): raw -> H_next ----------------
__global__ __launch_bounds__(256) void k_transform(const unsigned short* __restrict__ raw,
      const float* __restrict__ psum, const float* __restrict__ psq,
      const float* __restrict__ gamma, const float* __restrict__ beta,
      unsigned short* __restrict__ Hout){
  __shared__ float s_sc[HID], s_sf[HID];
  int t = threadIdx.x;
  if(t < HID){
    float s=0.f, s2=0.f;
    #pragma unroll
    for(int i=0;i<SPREAD;i++){ s += psum[i*HID+t]; s2 += psq[i*HID+t]; }
    float mu  = s  * (1.0f/(float)N_NODES);
    float var = s2 * (1.0f/(float)N_NODES) - mu*mu;
    float rstd = rsqrtf(var + BN_EPS);
    float sc = rstd * gamma[t];
    s_sc[t] = sc; s_sf[t] = beta[t] - mu*sc;
  }
  __syncthreads();
  int tid = blockIdx.x*256 + t;   // N_NODES*16 uint4 units
  if(tid >= N_NODES*16) return;
  int q = tid & 15;
  uint4 u = ((const uint4*)raw)[tid];
  float f0 = fmaxf(fmaf(bflo(u.x), s_sc[q*8+0], s_sf[q*8+0]), 0.f);
  float f1 = fmaxf(fmaf(bfhi(u.x), s_sc[q*8+1], s_sf[q*8+1]), 0.f);
  float f2 = fmaxf(fmaf(bflo(u.y), s_sc[q*8+2], s_sf[q*8+2]), 0.f);
  float f3 = fmaxf(fmaf(bfhi(u.y), s_sc[q*8+3], s_sf[q*8+3]), 0.f);
  float f4 = fmaxf(fmaf(bflo(u.z), s_sc[q*8+4], s_sf[q*8+4]), 0.f);
  float f5 = fmaxf(fmaf(bfhi(u.z), s_sc[q*8+5], s_sf[q*8+5]), 0.f);
  float f6 = fmaxf(fmaf(bflo(u.w), s_sc[q*8+6], s_sf[q*8+6]), 0.f);
  float f7 = fmaxf(fmaf(bfhi(u.w), s_sc[q*8+7], s_sf[q*8+7]), 0.f);
  uint4 o;
  o.x = fpack(f0,f1); o.y = fpack(f2,f3); o.z = fpack(f4,f5); o.w = fpack(f6,f7);
  ((uint4*)Hout)[tid] = o;
}

// ---------------- FUSED: global mean pool (one block per graph, no atomics) + BN2 + ReLU + MLP head ----------------
__global__ __launch_bounds__(256) void k_poolmlp(const unsigned short* __restrict__ raw,
      const int* __restrict__ gstart,
      const float* __restrict__ psum, const float* __restrict__ psq,
      const float* __restrict__ gamma, const float* __restrict__ beta,
      const float* __restrict__ fc1W, const float* __restrict__ fc1b,
      const float* __restrict__ fc2W, const float* __restrict__ fc2b,
      float* __restrict__ out){
  __shared__ float s_sc[HID], s_sf[HID];
  __shared__ float red[16][HID];
  __shared__ float p[HID];
  int g = blockIdx.x, t = threadIdx.x;
  if(t < HID){
    float s=0.f, s2=0.f;
    #pragma unroll
    for(int i=0;i<SPREAD;i++){ s += psum[i*HID+t]; s2 += psq[i*HID+t]; }
    float mu  = s  * (1.0f/(float)N_NODES);
    float var = s2 * (1.0f/(float)N_NODES) - mu*mu;
    float rstd = rsqrtf(var + BN_EPS);
    float sc = rstd * gamma[t];
    s_sc[t] = sc; s_sf[t] = beta[t] - mu*sc;
  }
  __syncthreads();
  int r0 = gstart[g], r1 = gstart[g+1];
  int q = t & 15, rr = t >> 4;   // 16 row-groups x 16 feature-slices
  float acc[8] = {0,0,0,0,0,0,0,0};
  for(int n = r0 + rr; n < r1; n += 16){
    uint4 u = ((const uint4*)raw)[(size_t)n*16 + q];
    acc[0] += fmaxf(fmaf(bflo(u.x), s_sc[q*8+0], s_sf[q*8+0]), 0.f);
    acc[1] += fmaxf(fmaf(bfhi(u.x), s_sc[q*8+1], s_sf[q*8+1]), 0.f);
    acc[2] += fmaxf(fmaf(bflo(u.y), s_sc[q*8+2], s_sf[q*8+2]), 0.f);
    acc[3] += fmaxf(fmaf(bfhi(u.y), s_sc[q*8+3], s_sf[q*8+3]), 0.f);
    acc[4] += fmaxf(fmaf(bflo(u.z), s_sc[q*8+4], s_sf[q*8+4]), 0.f);
    acc[5] += fmaxf(fmaf(bfhi(u.z), s_sc[q*8+5], s_sf[q*8+5]), 0.f);
    acc[6] += fmaxf(fmaf(bflo(u.w), s_sc[q*8+6], s_sf[q*8+6]), 0.f);
    acc[7] += fmaxf(fmaf(bfhi(u.w), s_sc[q*8+7], s_sf[q*8+7]), 0.f);
  }
  #pragma unroll
  for(int k=0;k<8;k++) red[rr][q*8+k] = acc[k];
  __syncthreads();
  if(t < HID){
    float s = 0.f;
    #pragma unroll
    for(int j=0;j<16;j++) s += red[j][t];
    float ic = 1.0f / fmaxf((float)(r1 - r0), 1.0f);
    p[t] = s * ic;
  }
  __syncthreads();
  if(t < 64){
    float z = fc1b[t];
    #pragma unroll 4
    for(int k=0;k<HID;k++) z += p[k]*fc1W[k*64 + t];
    z = fmaxf(z, 0.f);
    float v = z * fc2W[t];
    #pragma unroll
    for(int off=32; off>0; off>>=1) v += __shfl_down(v, off, 64);
    if(t==0) out[g] = 1.0f/(1.0f + expf(-(v + fc2b[0])));
  }
}

extern "C" void kernel_launch(void* const* d_in, const int* in_sizes, int n_in,
                              void* d_out, int out_size, void* d_ws, size_t ws_size,
                              hipStream_t stream){
  const float* x    = (const float*)d_in[0];
  const int*   ei   = (const int*)d_in[1];
  const int*   batch= (const int*)d_in[2];
  const float* Wn0=(const float*)d_in[3]; const float* Wr0=(const float*)d_in[4]; const float* b0=(const float*)d_in[5];
  const float* Wn1=(const float*)d_in[6]; const float* Wr1=(const float*)d_in[7]; const float* b1=(const float*)d_in[8];
  const float* Wn2=(const float*)d_in[9]; const float* Wr2=(const float*)d_in[10]; const float* b2=(const float*)d_in[11];
  const float* gamma=(const float*)d_in[12]; const float* beta=(const float*)d_in[13];
  const float* fc1W=(const float*)d_in[14]; const float* fc1b=(const float*)d_in[15];
  const float* fc2W=(const float*)d_in[16]; const float* fc2b=(const float*)d_in[17];
  float* out = (float*)d_out;

  char* ws = (char*)d_ws;
  size_t off = 0;
  auto alloc = [&](size_t bytes)->char*{ char* p = ws + off; off += (bytes + 255) & ~(size_t)255; return p; };

  // --- zeroed region (single memset): bcount | bfill | pstats ---
  char* zero0   = ws + off;
  int*   bcount = (int*)alloc((size_t)NB*4);
  int*   bfill  = (int*)alloc((size_t)NB*4);
  float* pstats = (float*)alloc((size_t)3*2*SPREAD*HID*4);
  size_t zbytes = (size_t)((ws + off) - zero0);

  // --- non-zeroed scratch ---
  unsigned short* H0  = (unsigned short*)alloc((size_t)N_NODES*IN_DIM*2);
  unsigned short* H1  = (unsigned short*)alloc((size_t)N_NODES*HID*2);
  unsigned short* H2  = (unsigned short*)alloc((size_t)N_NODES*HID*2);
  unsigned short* raw = (unsigned short*)alloc((size_t)N_NODES*HID*2);
  unsigned short* Bp0 = (unsigned short*)alloc((size_t)8*4*64*8*2);
  unsigned short* Bp1 = (unsigned short*)alloc((size_t)8*8*64*8*2);
  unsigned short* Bp2 = (unsigned short*)alloc((size_t)8*8*64*8*2);
  float* invdeg = (float*)alloc((size_t)N_NODES*4);
  int* rowptr   = (int*)alloc((size_t)(N_NODES+1)*4);
  unsigned short* eidx = (unsigned short*)alloc((size_t)N_EDGES*2);
  unsigned* pairs = (unsigned*)alloc((size_t)N_EDGES*4);
  int* gstart   = (int*)alloc((size_t)(NUM_GRAPHS+1)*4);

  auto psumL = [&](int l){ return pstats + (size_t)l*2*SPREAD*HID; };
  auto psqL  = [&](int l){ return pstats + (size_t)l*2*SPREAD*HID + (size_t)SPREAD*HID; };

  const int* src = ei;
  const int* dst = ei + N_EDGES;

  hipMemsetAsync(zero0, 0, zbytes, stream);

  // CSR build + packs + graph bounds (ride along with scatter dispatch)
  k_hist<<<NCHUNK, 256, 0, stream>>>(dst, bcount);
  k_scatter_pack<<<NCHUNK+PX_BLKS+W0_BLKS+2*W1_BLKS+GB_BLKS, 256, 0, stream>>>(src, dst, bcount, bfill, pairs,
      x, H0, Wn0, Wr0, Bp0, Wn1, Wr1, Bp1, Wn2, Wr2, Bp2, batch, gstart);
  k_csr<<<NB, 1024, 0, stream>>>(pairs, bcount, rowptr, invdeg, eidx);

  const int AG_BLKS = (N_NODES + 15)/16;   // 3125

  // ---- layer 0 ----
  k_agg_gemm<IN_DIM><<<AG_BLKS, 256, 0, stream>>>(H0, eidx, rowptr, invdeg, Bp0, b0, raw, psumL(0), psqL(0));
  k_transform<<<(N_NODES*16)/256, 256, 0, stream>>>(raw, psumL(0), psqL(0), gamma+0*HID, beta+0*HID, H1);
  // ---- layer 1 ----
  k_agg_gemm<HID><<<AG_BLKS, 256, 0, stream>>>(H1, eidx, rowptr, invdeg, Bp1, b1, raw, psumL(1), psqL(1));
  k_transform<<<(N_NODES*16)/256, 256, 0, stream>>>(raw, psumL(1), psqL(1), gamma+1*HID, beta+1*HID, H2);
  // ---- layer 2 ----
  k_agg_gemm<HID><<<AG_BLKS, 256, 0, stream>>>(H2, eidx, rowptr, invdeg, Bp2, b2, raw, psumL(2), psqL(2));

  // ---- fused pool + BN2 + ReLU + MLP head (one block per graph, no atomics) ----
  k_poolmlp<<<NUM_GRAPHS, 256, 0, stream>>>(raw, gstart, psumL(2), psqL(2), gamma+2*HID, beta+2*HID,
      fc1W, fc1b, fc2W, fc2b, out);
}